// Round 1
// baseline (1133.647 us; speedup 1.0000x reference)
//
#include <hip/hip_runtime.h>
#include <stdint.h>

#define NROWS 8192
#define DIM 512
#define BM 128
#define BN 256
#define BK 32

__device__ __forceinline__ uint32_t f2o(float f){
  uint32_t u = __float_as_uint(f);
  return (u & 0x80000000u) ? ~u : (u | 0x80000000u);
}
__device__ __forceinline__ float o2f(uint32_t o){
  uint32_t u = (o & 0x80000000u) ? (o & 0x7FFFFFFFu) : ~o;
  return __uint_as_float(u);
}

// norms of new rows (inv), and init of per-row best (packed argmax accumulator)
__global__ void knorm(const float* __restrict__ x, float* __restrict__ invn,
                      unsigned long long* __restrict__ best){
  int row = blockIdx.x * 4 + (threadIdx.x >> 6);
  int lane = threadIdx.x & 63;
  if (threadIdx.x < 4) best[blockIdx.x * 4 + threadIdx.x] = 0ULL;
  const float4* xr = (const float4*)(x + (size_t)row * DIM);
  float s = 0.f;
  #pragma unroll
  for (int k = 0; k < 2; ++k){
    float4 v = xr[lane + 64 * k];
    s += v.x * v.x + v.y * v.y + v.z * v.z + v.w * v.w;
  }
  #pragma unroll
  for (int off = 32; off > 0; off >>= 1) s += __shfl_down(s, off);
  if (lane == 0) invn[row] = 1.0f / fmaxf(sqrtf(s), 1e-8f);
}

// fused fp32 GEMM + per-row argmax (tie -> lowest j) via packed u64 atomicMax
__global__ __launch_bounds__(256, 2) void kargmax(
    const float* __restrict__ A, const float* __restrict__ B,
    const float* __restrict__ invn, unsigned long long* __restrict__ best){
  __shared__ float As[BM][BK];   // row-major: b128 stage writes + b128-over-k reads
  __shared__ float Bs[BK][BN];   // k-major: b128 reads over n
  const int t = threadIdx.x;
  const int tx = t & 15, ty = t >> 4;
  const int m0 = blockIdx.y * BM, n0 = blockIdx.x * BN;

  float acc[8][16];
  #pragma unroll
  for (int i = 0; i < 8; ++i)
    #pragma unroll
    for (int e = 0; e < 16; ++e) acc[i][e] = 0.f;

  const int lr = t >> 3;        // 0..31
  const int lk = (t & 7) * 4;   // 0,4,...,28

  for (int k0 = 0; k0 < DIM; k0 += BK){
    #pragma unroll
    for (int r = 0; r < 4; ++r){
      int mm = lr + r * 32;
      float4 v = *(const float4*)(A + (size_t)(m0 + mm) * DIM + k0 + lk);
      *(float4*)&As[mm][lk] = v;
    }
    #pragma unroll
    for (int r = 0; r < 8; ++r){
      int nn = lr + r * 32;
      float4 v = *(const float4*)(B + (size_t)(n0 + nn) * DIM + k0 + lk);
      Bs[lk + 0][nn] = v.x; Bs[lk + 1][nn] = v.y;
      Bs[lk + 2][nn] = v.z; Bs[lk + 3][nn] = v.w;
    }
    __syncthreads();
    #pragma unroll 2
    for (int k4 = 0; k4 < BK; k4 += 4){
      float4 a4[8];
      #pragma unroll
      for (int mi = 0; mi < 8; ++mi) a4[mi] = *(const float4*)&As[ty * 8 + mi][k4];
      #pragma unroll
      for (int kk = 0; kk < 4; ++kk){
        float b[16];
        #pragma unroll
        for (int q = 0; q < 4; ++q)
          *(float4*)&b[q * 4] = *(const float4*)&Bs[k4 + kk][q * 64 + tx * 4];
        #pragma unroll
        for (int mi = 0; mi < 8; ++mi){
          float av = (kk == 0) ? a4[mi].x : (kk == 1) ? a4[mi].y
                   : (kk == 2) ? a4[mi].z : a4[mi].w;
          #pragma unroll
          for (int e = 0; e < 16; ++e)
            acc[mi][e] = fmaf(av, b[e], acc[mi][e]);
        }
      }
    }
    __syncthreads();
  }

  float inv[16];
  #pragma unroll
  for (int q = 0; q < 4; ++q)
    #pragma unroll
    for (int jj = 0; jj < 4; ++jj)
      inv[q * 4 + jj] = invn[n0 + q * 64 + tx * 4 + jj];

  #pragma unroll
  for (int mi = 0; mi < 8; ++mi){
    float bv = -3.0e38f; int bj = 0;
    #pragma unroll
    for (int e = 0; e < 16; ++e){     // ascending j within thread -> strict > keeps first
      int q = e >> 2, jj = e & 3;
      int j = n0 + q * 64 + tx * 4 + jj;
      float v = acc[mi][e] * inv[e];
      if (v > bv){ bv = v; bj = j; }
    }
    #pragma unroll
    for (int m = 1; m < 16; m <<= 1){
      float ov = __shfl_xor(bv, m, 16);
      int oj = __shfl_xor(bj, m, 16);
      if (ov > bv || (ov == bv && oj < bj)){ bv = ov; bj = oj; }
    }
    if (tx == 0){
      unsigned long long pk = ((unsigned long long)f2o(bv) << 32)
                            | (unsigned long long)(0xFFFFFFFFu - (uint32_t)bj);
      atomicMax(&best[m0 + ty * 8 + mi], pk);
    }
  }
}

// expanded[i][:] = new[idx[i]][:]  (staged into d_out, consumed by ksort)
__global__ void kexpand(const float* __restrict__ newe,
                        const unsigned long long* __restrict__ best,
                        float* __restrict__ expd){
  int i = blockIdx.x * 2 + (threadIdx.x >> 7);
  int c = (threadIdx.x & 127) * 4;
  int j = (int)(0xFFFFFFFFu - (uint32_t)(best[i] & 0xFFFFFFFFull));
  *(float4*)(expd + (size_t)i * DIM + c) =
      *(const float4*)(newe + (size_t)j * DIM + c);
}

// per-column: bitonic sort old values (u32) and (expanded,row) keys (u64),
// then fused OT-align + final blend, scattered to out. expd_out aliases d_out:
// column is fully loaded into LDS before being overwritten.
__global__ __launch_bounds__(1024) void ksort(
    const float* __restrict__ olde, const float* __restrict__ newe,
    float* expd_out){
  __shared__ uint32_t kA[NROWS];              // 32 KB
  __shared__ unsigned long long kB[NROWS];    // 64 KB
  const int c = blockIdx.x;
  const int t = threadIdx.x;
  for (int r = t; r < NROWS; r += 1024){
    kA[r] = f2o(olde[(size_t)r * DIM + c]);
    kB[r] = ((unsigned long long)f2o(expd_out[(size_t)r * DIM + c]) << 32)
          | (unsigned)r;                       // unique keys => stable order
  }
  __syncthreads();
  for (int k = 2; k <= NROWS; k <<= 1){
    for (int j = k >> 1; j > 0; j >>= 1){
      #pragma unroll 1
      for (int s = 0; s < NROWS / 2; s += 1024){
        int p = s + t;
        int i1 = ((p & ~(j - 1)) << 1) | (p & (j - 1));
        int i2 = i1 | j;
        bool up = ((i1 & k) == 0);
        uint32_t x = kA[i1], y = kA[i2];
        if ((x > y) == up){ kA[i1] = y; kA[i2] = x; }
        unsigned long long bx = kB[i1], by = kB[i2];
        if ((bx > by) == up){ kB[i1] = by; kB[i2] = bx; }
      }
      __syncthreads();
    }
  }
  for (int r = t; r < NROWS; r += 1024){
    unsigned long long kb = kB[r];
    int row = (int)(uint32_t)(kb & 0xFFFFFFFFull);
    float expv = o2f((uint32_t)(kb >> 32));
    float hsrc = o2f(kA[r]);                       // sorted old at same rank
    float aligned = expv + 0.05f * (hsrc - expv);  // expanded + alpha*(h_src - h_tgt)
    float nv = newe[(size_t)row * DIM + c];
    expd_out[(size_t)row * DIM + c] = 0.95f * nv + 0.05f * aligned;
  }
}

extern "C" void kernel_launch(void* const* d_in, const int* in_sizes, int n_in,
                              void* d_out, int out_size, void* d_ws, size_t ws_size,
                              hipStream_t stream){
  const float* olde = (const float*)d_in[0];
  const float* newe = (const float*)d_in[1];
  float* out = (float*)d_out;
  unsigned long long* best = (unsigned long long*)d_ws;               // 64 KB
  float* invn = (float*)((char*)d_ws + NROWS * sizeof(unsigned long long)); // 32 KB

  knorm<<<NROWS / 4, 256, 0, stream>>>(newe, invn, best);
  kargmax<<<dim3(NROWS / BN, NROWS / BM), 256, 0, stream>>>(olde, newe, invn, best);
  kexpand<<<NROWS / 2, 256, 0, stream>>>(newe, best, out);
  ksort<<<DIM, 1024, 0, stream>>>(olde, newe, out);
}

// Round 2
// 525.089 us; speedup vs baseline: 2.1590x; 2.1590x over previous
//
#include <hip/hip_runtime.h>
#include <hip/hip_bf16.h>
#include <stdint.h>

#define NROWS 8192
#define DIM 512
#define MARGIN 0.03f
#define OVF_CAP 64

typedef unsigned long long u64;
typedef uint32_t u32;
using bf16x8 = __attribute__((ext_vector_type(8))) short;
using f32x4 = __attribute__((ext_vector_type(4))) float;

__device__ __forceinline__ u32 f2o(float f){
  u32 u = __float_as_uint(f);
  return (u & 0x80000000u) ? ~u : (u | 0x80000000u);
}
__device__ __forceinline__ float o2f(u32 o){
  u32 u = (o & 0x80000000u) ? (o & 0x7FFFFFFFu) : ~o;
  return __uint_as_float(u);
}
__device__ __forceinline__ short bfbits(float f){
  __hip_bfloat16 h = __float2bfloat16(f);
  return *reinterpret_cast<short*>(&h);
}

// inv norms of new rows + zero the per-row overflow counters
__global__ void knorm(const float* __restrict__ x, float* __restrict__ invn,
                      u32* __restrict__ cnt){
  int row = blockIdx.x * 4 + (threadIdx.x >> 6);
  int lane = threadIdx.x & 63;
  if (threadIdx.x < 4) cnt[blockIdx.x * 4 + threadIdx.x] = 0u;
  const float4* xr = (const float4*)(x + (size_t)row * DIM);
  float s = 0.f;
  #pragma unroll
  for (int k = 0; k < 2; ++k){
    float4 v = xr[lane + 64 * k];
    s += v.x * v.x + v.y * v.y + v.z * v.z + v.w * v.w;
  }
  #pragma unroll
  for (int off = 32; off > 0; off >>= 1) s += __shfl_down(s, off);
  if (lane == 0) invn[row] = 1.0f / fmaxf(sqrtf(s), 1e-8f);
}

// Stage 1: bf16 MFMA GEMM; per row per 128-col tile emit packed tile-argmax
// (plain store) + margin candidates (atomic append). fp32->bf16 on the fly.
__global__ __launch_bounds__(256) void kgemm(
    const float* __restrict__ A, const float* __restrict__ B,
    const float* __restrict__ invn, u64* __restrict__ Tt,
    u64* __restrict__ ovf, u32* __restrict__ cnt){
  __shared__ short As[128 * 40];   // 32 bf16/row padded to 40 (80B) -> 2-way banks only
  __shared__ short Bs[128 * 40];
  const int t = threadIdx.x;
  const int lane = t & 63, w = t >> 6;
  const int c16 = lane & 15, g = lane >> 4;
  const int m0 = blockIdx.y * 128, n0 = blockIdx.x * 128;

  f32x4 acc[2][8];
  #pragma unroll
  for (int mi = 0; mi < 2; ++mi)
    #pragma unroll
    for (int nj = 0; nj < 8; ++nj) acc[mi][nj] = {0.f, 0.f, 0.f, 0.f};

  for (int k0 = 0; k0 < DIM; k0 += 32){
    #pragma unroll
    for (int it = 0; it < 2; ++it){
      int s = t + it * 256;
      int row = s >> 2, part = s & 3;       // 4 lanes cover one row's 128B: coalesced
      const float4* ga = (const float4*)(A + (size_t)(m0 + row) * DIM + k0 + part * 8);
      float4 a0 = ga[0], a1 = ga[1];
      bf16x8 ha = { bfbits(a0.x), bfbits(a0.y), bfbits(a0.z), bfbits(a0.w),
                    bfbits(a1.x), bfbits(a1.y), bfbits(a1.z), bfbits(a1.w) };
      *(bf16x8*)(&As[row * 40 + part * 8]) = ha;
      const float4* gb = (const float4*)(B + (size_t)(n0 + row) * DIM + k0 + part * 8);
      float4 b0 = gb[0], b1 = gb[1];
      bf16x8 hb = { bfbits(b0.x), bfbits(b0.y), bfbits(b0.z), bfbits(b0.w),
                    bfbits(b1.x), bfbits(b1.y), bfbits(b1.z), bfbits(b1.w) };
      *(bf16x8*)(&Bs[row * 40 + part * 8]) = hb;
    }
    __syncthreads();
    bf16x8 af[2], bf[8];
    #pragma unroll
    for (int mi = 0; mi < 2; ++mi)
      af[mi] = *(const bf16x8*)(&As[(w * 32 + mi * 16 + c16) * 40 + g * 8]);
    #pragma unroll
    for (int nj = 0; nj < 8; ++nj)
      bf[nj] = *(const bf16x8*)(&Bs[(nj * 16 + c16) * 40 + g * 8]);
    #pragma unroll
    for (int mi = 0; mi < 2; ++mi)
      #pragma unroll
      for (int nj = 0; nj < 8; ++nj)
        acc[mi][nj] = __builtin_amdgcn_mfma_f32_16x16x32_bf16(af[mi], bf[nj], acc[mi][nj], 0, 0, 0);
    __syncthreads();
  }

  float invc[8];
  #pragma unroll
  for (int nj = 0; nj < 8; ++nj) invc[nj] = invn[n0 + nj * 16 + c16];

  #pragma unroll
  for (int mi = 0; mi < 2; ++mi){
    #pragma unroll
    for (int reg = 0; reg < 4; ++reg){
      float bv = -3.4e38f; int bj = 0;
      #pragma unroll
      for (int nj = 0; nj < 8; ++nj){       // ascending j in-thread: strict > keeps lowest
        float v = acc[mi][nj][reg] * invc[nj];
        if (v > bv){ bv = v; bj = nj; }
      }
      int gj = n0 + bj * 16 + c16;
      u64 pk = ((u64)f2o(bv) << 32) | (u32)(~(u32)gj);
      #pragma unroll
      for (int m = 1; m < 16; m <<= 1){     // reduce across the 16 cols of this row
        u64 o = __shfl_xor(pk, m);
        pk = pk > o ? pk : o;
      }
      int grow = m0 + w * 32 + mi * 16 + g * 4 + reg;
      if (c16 == 0) Tt[(size_t)grow * 64 + blockIdx.x] = pk;
      float thr = o2f((u32)(pk >> 32)) - MARGIN;
      int tj = (int)~((u32)pk);
      #pragma unroll
      for (int nj = 0; nj < 8; ++nj){
        float v = acc[mi][nj][reg] * invc[nj];
        int j = n0 + nj * 16 + c16;
        if (v >= thr && j != tj){
          u32 pos = atomicAdd(&cnt[grow], 1u);
          if (pos < OVF_CAP) ovf[(size_t)grow * OVF_CAP + pos] = ((u64)f2o(v) << 32) | (u32)j;
        }
      }
    }
  }
}

// Stage 2: one wave per row. Fast path if a single candidate in the margin
// window; else exact fp32 dots for all window candidates (lowest-j ties).
__global__ __launch_bounds__(256) void kresolve(
    const float* __restrict__ A, const float* __restrict__ B,
    const float* __restrict__ invn, const u64* __restrict__ Tt,
    const u64* __restrict__ ovf, const u32* __restrict__ cnt,
    int* __restrict__ idx){
  const int r = blockIdx.x * 4 + (threadIdx.x >> 6);
  const int lane = threadIdx.x & 63;
  u64 e = Tt[(size_t)r * 64 + lane];
  u64 m = e;
  #pragma unroll
  for (int s = 1; s < 64; s <<= 1){ u64 o = __shfl_xor(m, s); m = m > o ? m : o; }
  float W = o2f((u32)(m >> 32)) - MARGIN;
  bool inw = o2f((u32)(e >> 32)) >= W;
  u64 bal = __ballot(inw);
  u32 nov_raw = cnt[r];
  int nov = nov_raw > OVF_CAP ? OVF_CAP : (int)nov_raw;
  u64 oe = (lane < nov) ? ovf[(size_t)r * OVF_CAP + lane] : 0ull;
  bool oin = (lane < nov) && (o2f((u32)(oe >> 32)) >= W);
  u64 bal2 = __ballot(oin);
  if (nov_raw <= OVF_CAP && __popcll(bal) == 1 && bal2 == 0ull){
    if (lane == 0) idx[r] = (int)~((u32)m);
    return;
  }
  const float* ar = A + (size_t)r * DIM;
  u64 best = 0ull;
  auto eval = [&](int j){
    const float* br = B + (size_t)j * DIM;
    float s = 0.f;
    for (int k = lane; k < DIM; k += 64) s = fmaf(ar[k], br[k], s);
    #pragma unroll
    for (int o = 32; o > 0; o >>= 1) s += __shfl_xor(s, o);
    s *= invn[j];
    u64 p = ((u64)f2o(s) << 32) | (u32)(~(u32)j);
    best = best > p ? best : p;
  };
  if (nov_raw > OVF_CAP){
    for (int j = 0; j < NROWS; ++j) eval(j);   // safety net, statistically unreachable
  } else {
    u64 mm = bal;
    while (mm){
      int b = __ffsll((unsigned long long)mm) - 1;
      int j = (int)~((u32)__shfl(e, b));
      eval(j);
      mm &= mm - 1;
    }
    mm = bal2;
    while (mm){
      int b = __ffsll((unsigned long long)mm) - 1;
      int j = (int)(u32)__shfl(oe, b);
      eval(j);
      mm &= mm - 1;
    }
  }
  if (lane == 0) idx[r] = (int)~((u32)best);
}

// expanded[i][:] = new[idx[i]][:]  (staged into d_out, consumed by ksort)
__global__ void kexpand(const float* __restrict__ newe, const int* __restrict__ idx,
                        float* __restrict__ expd){
  int i = blockIdx.x * 2 + (threadIdx.x >> 7);
  int c = (threadIdx.x & 127) * 4;
  int j = idx[i];
  *(float4*)(expd + (size_t)i * DIM + c) =
      *(const float4*)(newe + (size_t)j * DIM + c);
}

// per-column bitonic sort + fused OT-align + final blend (unchanged, passing)
__global__ __launch_bounds__(1024) void ksort(
    const float* __restrict__ olde, const float* __restrict__ newe,
    float* expd_out){
  __shared__ u32 kA[NROWS];
  __shared__ u64 kB[NROWS];
  const int c = blockIdx.x;
  const int t = threadIdx.x;
  for (int r = t; r < NROWS; r += 1024){
    kA[r] = f2o(olde[(size_t)r * DIM + c]);
    kB[r] = ((u64)f2o(expd_out[(size_t)r * DIM + c]) << 32) | (unsigned)r;
  }
  __syncthreads();
  for (int k = 2; k <= NROWS; k <<= 1){
    for (int j = k >> 1; j > 0; j >>= 1){
      #pragma unroll 1
      for (int s = 0; s < NROWS / 2; s += 1024){
        int p = s + t;
        int i1 = ((p & ~(j - 1)) << 1) | (p & (j - 1));
        int i2 = i1 | j;
        bool up = ((i1 & k) == 0);
        u32 x = kA[i1], y = kA[i2];
        if ((x > y) == up){ kA[i1] = y; kA[i2] = x; }
        u64 bx = kB[i1], by = kB[i2];
        if ((bx > by) == up){ kB[i1] = by; kB[i2] = bx; }
      }
      __syncthreads();
    }
  }
  for (int r = t; r < NROWS; r += 1024){
    u64 kb = kB[r];
    int row = (int)(u32)(kb & 0xFFFFFFFFull);
    float expv = o2f((u32)(kb >> 32));
    float hsrc = o2f(kA[r]);
    float aligned = expv + 0.05f * (hsrc - expv);
    float nv = newe[(size_t)row * DIM + c];
    expd_out[(size_t)row * DIM + c] = 0.95f * nv + 0.05f * aligned;
  }
}

extern "C" void kernel_launch(void* const* d_in, const int* in_sizes, int n_in,
                              void* d_out, int out_size, void* d_ws, size_t ws_size,
                              hipStream_t stream){
  const float* olde = (const float*)d_in[0];
  const float* newe = (const float*)d_in[1];
  float* out = (float*)d_out;
  int* idx = (int*)d_ws;                                      // 32 KB
  float* invn = (float*)((char*)d_ws + NROWS * sizeof(int));  // 32 KB
  // Stage-1 scratch lives in d_out; fully consumed before kexpand overwrites it.
  u64* Tt  = (u64*)d_out;                                          // 4 MB
  u64* ovf = (u64*)((char*)d_out + (size_t)NROWS * 64 * 8);        // 4 MB
  u32* cnt = (u32*)((char*)d_out + (size_t)NROWS * 64 * 8 * 2);    // 32 KB

  knorm<<<NROWS / 4, 256, 0, stream>>>(newe, invn, cnt);
  kgemm<<<dim3(64, 64), 256, 0, stream>>>(olde, newe, invn, Tt, ovf, cnt);
  kresolve<<<NROWS / 4, 256, 0, stream>>>(olde, newe, invn, Tt, ovf, cnt, idx);
  kexpand<<<NROWS / 2, 256, 0, stream>>>(newe, idx, out);
  ksort<<<DIM, 1024, 0, stream>>>(olde, newe, out);
}

// Round 3
// 340.209 us; speedup vs baseline: 3.3322x; 1.5434x over previous
//
#include <hip/hip_runtime.h>
#include <hip/hip_bf16.h>
#include <stdint.h>

#define NROWS 8192
#define DIM 512
#define MARGIN 0.03f
#define OVF_CAP 64

typedef unsigned long long u64;
typedef uint32_t u32;
using bf16x8 = __attribute__((ext_vector_type(8))) short;
using f32x4 = __attribute__((ext_vector_type(4))) float;

__device__ __forceinline__ u32 f2o(float f){
  u32 u = __float_as_uint(f);
  return (u & 0x80000000u) ? ~u : (u | 0x80000000u);
}
__device__ __forceinline__ float o2f(u32 o){
  u32 u = (o & 0x80000000u) ? (o & 0x7FFFFFFFu) : ~o;
  return __uint_as_float(u);
}
__device__ __forceinline__ short bfbits(float f){
  __hip_bfloat16 h = __float2bfloat16(f);
  return *reinterpret_cast<short*>(&h);
}

// inv norms of new rows + zero the per-row overflow counters
__global__ void knorm(const float* __restrict__ x, float* __restrict__ invn,
                      u32* __restrict__ cnt){
  int row = blockIdx.x * 4 + (threadIdx.x >> 6);
  int lane = threadIdx.x & 63;
  if (threadIdx.x < 4) cnt[blockIdx.x * 4 + threadIdx.x] = 0u;
  const float4* xr = (const float4*)(x + (size_t)row * DIM);
  float s = 0.f;
  #pragma unroll
  for (int k = 0; k < 2; ++k){
    float4 v = xr[lane + 64 * k];
    s += v.x * v.x + v.y * v.y + v.z * v.z + v.w * v.w;
  }
  #pragma unroll
  for (int off = 32; off > 0; off >>= 1) s += __shfl_down(s, off);
  if (lane == 0) invn[row] = 1.0f / fmaxf(sqrtf(s), 1e-8f);
}

// Stage 1: bf16 MFMA GEMM; per row per 128-col tile emit packed tile-argmax
// (plain store) + margin candidates (atomic append). fp32->bf16 on the fly.
__global__ __launch_bounds__(256) void kgemm(
    const float* __restrict__ A, const float* __restrict__ B,
    const float* __restrict__ invn, u64* __restrict__ Tt,
    u64* __restrict__ ovf, u32* __restrict__ cnt){
  __shared__ short As[128 * 40];   // 32 bf16/row padded to 40 (80B) -> 2-way banks only
  __shared__ short Bs[128 * 40];
  const int t = threadIdx.x;
  const int lane = t & 63, w = t >> 6;
  const int c16 = lane & 15, g = lane >> 4;
  const int m0 = blockIdx.y * 128, n0 = blockIdx.x * 128;

  f32x4 acc[2][8];
  #pragma unroll
  for (int mi = 0; mi < 2; ++mi)
    #pragma unroll
    for (int nj = 0; nj < 8; ++nj) acc[mi][nj] = {0.f, 0.f, 0.f, 0.f};

  for (int k0 = 0; k0 < DIM; k0 += 32){
    #pragma unroll
    for (int it = 0; it < 2; ++it){
      int s = t + it * 256;
      int row = s >> 2, part = s & 3;       // 4 lanes cover one row's 128B: coalesced
      const float4* ga = (const float4*)(A + (size_t)(m0 + row) * DIM + k0 + part * 8);
      float4 a0 = ga[0], a1 = ga[1];
      bf16x8 ha = { bfbits(a0.x), bfbits(a0.y), bfbits(a0.z), bfbits(a0.w),
                    bfbits(a1.x), bfbits(a1.y), bfbits(a1.z), bfbits(a1.w) };
      *(bf16x8*)(&As[row * 40 + part * 8]) = ha;
      const float4* gb = (const float4*)(B + (size_t)(n0 + row) * DIM + k0 + part * 8);
      float4 b0 = gb[0], b1 = gb[1];
      bf16x8 hb = { bfbits(b0.x), bfbits(b0.y), bfbits(b0.z), bfbits(b0.w),
                    bfbits(b1.x), bfbits(b1.y), bfbits(b1.z), bfbits(b1.w) };
      *(bf16x8*)(&Bs[row * 40 + part * 8]) = hb;
    }
    __syncthreads();
    bf16x8 af[2], bf[8];
    #pragma unroll
    for (int mi = 0; mi < 2; ++mi)
      af[mi] = *(const bf16x8*)(&As[(w * 32 + mi * 16 + c16) * 40 + g * 8]);
    #pragma unroll
    for (int nj = 0; nj < 8; ++nj)
      bf[nj] = *(const bf16x8*)(&Bs[(nj * 16 + c16) * 40 + g * 8]);
    #pragma unroll
    for (int mi = 0; mi < 2; ++mi)
      #pragma unroll
      for (int nj = 0; nj < 8; ++nj)
        acc[mi][nj] = __builtin_amdgcn_mfma_f32_16x16x32_bf16(af[mi], bf[nj], acc[mi][nj], 0, 0, 0);
    __syncthreads();
  }

  float invc[8];
  #pragma unroll
  for (int nj = 0; nj < 8; ++nj) invc[nj] = invn[n0 + nj * 16 + c16];

  #pragma unroll
  for (int mi = 0; mi < 2; ++mi){
    #pragma unroll
    for (int reg = 0; reg < 4; ++reg){
      float bv = -3.4e38f; int bj = 0;
      #pragma unroll
      for (int nj = 0; nj < 8; ++nj){       // ascending j in-thread: strict > keeps lowest
        float v = acc[mi][nj][reg] * invc[nj];
        if (v > bv){ bv = v; bj = nj; }
      }
      int gj = n0 + bj * 16 + c16;
      u64 pk = ((u64)f2o(bv) << 32) | (u32)(~(u32)gj);
      #pragma unroll
      for (int m = 1; m < 16; m <<= 1){     // reduce across the 16 cols of this row
        u64 o = __shfl_xor(pk, m);
        pk = pk > o ? pk : o;
      }
      int grow = m0 + w * 32 + mi * 16 + g * 4 + reg;
      if (c16 == 0) Tt[(size_t)grow * 64 + blockIdx.x] = pk;
      float thr = o2f((u32)(pk >> 32)) - MARGIN;
      int tj = (int)~((u32)pk);
      #pragma unroll
      for (int nj = 0; nj < 8; ++nj){
        float v = acc[mi][nj][reg] * invc[nj];
        int j = n0 + nj * 16 + c16;
        if (v >= thr && j != tj){
          u32 pos = atomicAdd(&cnt[grow], 1u);
          if (pos < OVF_CAP) ovf[(size_t)grow * OVF_CAP + pos] = ((u64)f2o(v) << 32) | (u32)j;
        }
      }
    }
  }
}

// Stage 2: one wave per row. Fast path if a single candidate in the margin
// window; else exact fp32 dots for all window candidates (lowest-j ties).
__global__ __launch_bounds__(256) void kresolve(
    const float* __restrict__ A, const float* __restrict__ B,
    const float* __restrict__ invn, const u64* __restrict__ Tt,
    const u64* __restrict__ ovf, const u32* __restrict__ cnt,
    int* __restrict__ idx){
  const int r = blockIdx.x * 4 + (threadIdx.x >> 6);
  const int lane = threadIdx.x & 63;
  u64 e = Tt[(size_t)r * 64 + lane];
  u64 m = e;
  #pragma unroll
  for (int s = 1; s < 64; s <<= 1){ u64 o = __shfl_xor(m, s); m = m > o ? m : o; }
  float W = o2f((u32)(m >> 32)) - MARGIN;
  bool inw = o2f((u32)(e >> 32)) >= W;
  u64 bal = __ballot(inw);
  u32 nov_raw = cnt[r];
  int nov = nov_raw > OVF_CAP ? OVF_CAP : (int)nov_raw;
  u64 oe = (lane < nov) ? ovf[(size_t)r * OVF_CAP + lane] : 0ull;
  bool oin = (lane < nov) && (o2f((u32)(oe >> 32)) >= W);
  u64 bal2 = __ballot(oin);
  if (nov_raw <= OVF_CAP && __popcll(bal) == 1 && bal2 == 0ull){
    if (lane == 0) idx[r] = (int)~((u32)m);
    return;
  }
  const float* ar = A + (size_t)r * DIM;
  u64 best = 0ull;
  auto eval = [&](int j){
    const float* br = B + (size_t)j * DIM;
    float s = 0.f;
    for (int k = lane; k < DIM; k += 64) s = fmaf(ar[k], br[k], s);
    #pragma unroll
    for (int o = 32; o > 0; o >>= 1) s += __shfl_xor(s, o);
    s *= invn[j];
    u64 p = ((u64)f2o(s) << 32) | (u32)(~(u32)j);
    best = best > p ? best : p;
  };
  if (nov_raw > OVF_CAP){
    for (int j = 0; j < NROWS; ++j) eval(j);   // safety net, statistically unreachable
  } else {
    u64 mm = bal;
    while (mm){
      int b = __ffsll((unsigned long long)mm) - 1;
      int j = (int)~((u32)__shfl(e, b));
      eval(j);
      mm &= mm - 1;
    }
    mm = bal2;
    while (mm){
      int b = __ffsll((unsigned long long)mm) - 1;
      int j = (int)(u32)__shfl(oe, b);
      eval(j);
      mm &= mm - 1;
    }
  }
  if (lane == 0) idx[r] = (int)~((u32)best);
}

// expanded[i][:] = new[idx[i]][:]  (staged into d_out, consumed by ksort)
__global__ void kexpand(const float* __restrict__ newe, const int* __restrict__ idx,
                        float* __restrict__ expd){
  int i = blockIdx.x * 2 + (threadIdx.x >> 7);
  int c = (threadIdx.x & 127) * 4;
  int j = idx[i];
  *(float4*)(expd + (size_t)i * DIM + c) =
      *(const float4*)(newe + (size_t)j * DIM + c);
}

// ---------------- LDS radix sort (stable, 8-bit digits) ----------------
// One radix pass over 8192 elements held in LDS. 1024 threads = 16 waves,
// each wave owns a contiguous block of 512 elements, iterated as 8 groups
// of 64 in (k, lane) order so ballot-ranking preserves element order.
template<bool HASPAY>
__device__ __forceinline__ void radix_pass(
    u32* srcK, u32* srcP, u32* dstK, u32* dstP,
    u32* hist, u32* totals, u32* digitbase,
    int shift, int w, int lane, int t){
  for (int i = t; i < 4096; i += 1024) hist[i] = 0;
  __syncthreads();
  u32 kreg[8], preg[8], dloc[8];
  #pragma unroll
  for (int k = 0; k < 8; ++k){
    int e = w * 512 + k * 64 + lane;
    u32 key = srcK[e];
    if (HASPAY) preg[k] = srcP[e];
    kreg[k] = key;
    u32 d = (key >> shift) & 255u;
    u64 m = ~0ull;
    #pragma unroll
    for (int b = 0; b < 8; ++b){
      u64 bb = __ballot((d >> b) & 1u);
      m &= ((d >> b) & 1u) ? bb : ~bb;
    }
    int leader = __ffsll((unsigned long long)m) - 1;
    u32 rank = (u32)__popcll(m & ((1ull << lane) - 1ull));
    u32 cntg = (u32)__popcll(m);
    u32 old = 0;
    if (lane == leader){ old = hist[w * 256 + d]; hist[w * 256 + d] = old + cntg; }
    old = (u32)__shfl((int)old, leader);
    dloc[k] = (d << 16) | (old + rank);
  }
  __syncthreads();
  if (t < 256){                         // per-bin exclusive prefix across waves
    u32 run = 0;
    #pragma unroll
    for (int ww = 0; ww < 16; ++ww){
      u32 v = hist[ww * 256 + t];
      hist[ww * 256 + t] = run;
      run += v;
    }
    totals[t] = run;
  }
  __syncthreads();
  if (t < 64){                          // exclusive scan of 256 bin totals (wave 0)
    u32 carry = 0;
    #pragma unroll
    for (int ch = 0; ch < 4; ++ch){
      u32 v = totals[ch * 64 + t];
      u32 inc = v;
      #pragma unroll
      for (int off = 1; off < 64; off <<= 1){
        u32 o = (u32)__shfl_up((int)inc, off);
        if (t >= off) inc += o;
      }
      digitbase[ch * 64 + t] = carry + inc - v;
      carry += (u32)__shfl((int)inc, 63);
    }
  }
  __syncthreads();
  #pragma unroll
  for (int k = 0; k < 8; ++k){
    u32 d = dloc[k] >> 16, off = dloc[k] & 0xFFFFu;
    u32 dst = digitbase[d] + hist[w * 256 + d] + off;
    dstK[dst] = kreg[k];
    if (HASPAY) dstP[dst] = preg[k];
  }
  __syncthreads();
}

// per-column: radix-sort expanded (stable, with row payload) and old (keys),
// compute 0.05*aligned and scatter to out[row][c] via LDS re-order.
// XCD-grouped columns: bid&7 selects XCD, 64 consecutive cols per XCD.
__global__ __launch_bounds__(1024) void ksort(
    const float* __restrict__ olde, float* expd_out){
  __shared__ u32 buf0[NROWS], buf1[NROWS], pay0[NROWS], pay1[NROWS]; // 128 KB
  __shared__ u32 hist[4096], totals[256], digitbase[256];            // 18 KB
  const int bid = blockIdx.x;
  const int c = (bid & 7) * 64 + (bid >> 3);   // XCD-grouped column
  const int t = threadIdx.x;
  const int lane = t & 63, w = t >> 6;

  for (int e = t; e < NROWS; e += 1024){       // row-ascending load order = stability
    buf0[e] = f2o(expd_out[(size_t)e * DIM + c]);
    pay0[e] = (u32)e;
  }
  __syncthreads();
  radix_pass<true>(buf0, pay0, buf1, pay1, hist, totals, digitbase, 0,  w, lane, t);
  radix_pass<true>(buf1, pay1, buf0, pay0, hist, totals, digitbase, 8,  w, lane, t);
  radix_pass<true>(buf0, pay0, buf1, pay1, hist, totals, digitbase, 16, w, lane, t);
  radix_pass<true>(buf1, pay1, buf0, pay0, hist, totals, digitbase, 24, w, lane, t);
  // sorted expanded keys in buf0, original rows in pay0; buf1/pay1 free
  for (int e = t; e < NROWS; e += 1024)
    buf1[e] = f2o(olde[(size_t)e * DIM + c]);
  __syncthreads();
  radix_pass<false>(buf1, pay1, pay1, buf1, hist, totals, digitbase, 0,  w, lane, t);
  radix_pass<false>(pay1, buf1, buf1, pay1, hist, totals, digitbase, 8,  w, lane, t);
  radix_pass<false>(buf1, pay1, pay1, buf1, hist, totals, digitbase, 16, w, lane, t);
  radix_pass<false>(pay1, buf1, buf1, pay1, hist, totals, digitbase, 24, w, lane, t);
  // sorted old values in buf1; pay1 free -> use as row-indexed staging
  for (int e = t; e < NROWS; e += 1024){
    u32 row = pay0[e];
    float expv = o2f(buf0[e]);
    float hsrc = o2f(buf1[e]);
    float aligned = expv + 0.05f * (hsrc - expv);
    pay1[row] = __float_as_uint(0.05f * aligned);
  }
  __syncthreads();
  for (int e = t; e < NROWS; e += 1024)        // row-ascending global writes
    expd_out[(size_t)e * DIM + c] = __uint_as_float(pay1[e]);
}

// out = 0.95*new + out   (out holds 0.05*aligned), fully coalesced
__global__ void kfinal(const float* __restrict__ newe, float* __restrict__ out){
  size_t i = (size_t)blockIdx.x * 256 + threadIdx.x;
  float4 n4 = ((const float4*)newe)[i];
  float4 o4 = ((float4*)out)[i];
  o4.x = fmaf(0.95f, n4.x, o4.x);
  o4.y = fmaf(0.95f, n4.y, o4.y);
  o4.z = fmaf(0.95f, n4.z, o4.z);
  o4.w = fmaf(0.95f, n4.w, o4.w);
  ((float4*)out)[i] = o4;
}

extern "C" void kernel_launch(void* const* d_in, const int* in_sizes, int n_in,
                              void* d_out, int out_size, void* d_ws, size_t ws_size,
                              hipStream_t stream){
  const float* olde = (const float*)d_in[0];
  const float* newe = (const float*)d_in[1];
  float* out = (float*)d_out;
  int* idx = (int*)d_ws;                                      // 32 KB
  float* invn = (float*)((char*)d_ws + NROWS * sizeof(int));  // 32 KB
  // Stage-1 scratch lives in d_out; fully consumed before kexpand overwrites it.
  u64* Tt  = (u64*)d_out;                                          // 4 MB
  u64* ovf = (u64*)((char*)d_out + (size_t)NROWS * 64 * 8);        // 4 MB
  u32* cnt = (u32*)((char*)d_out + (size_t)NROWS * 64 * 8 * 2);    // 32 KB

  knorm<<<NROWS / 4, 256, 0, stream>>>(newe, invn, cnt);
  kgemm<<<dim3(64, 64), 256, 0, stream>>>(olde, newe, invn, Tt, ovf, cnt);
  kresolve<<<NROWS / 4, 256, 0, stream>>>(olde, newe, invn, Tt, ovf, cnt, idx);
  kexpand<<<NROWS / 2, 256, 0, stream>>>(newe, idx, out);
  ksort<<<DIM, 1024, 0, stream>>>(olde, out);
  kfinal<<<NROWS * DIM / 4 / 256, 256, 0, stream>>>(newe, out);
}

// Round 4
// 300.812 us; speedup vs baseline: 3.7686x; 1.1310x over previous
//
#include <hip/hip_runtime.h>
#include <hip/hip_bf16.h>
#include <stdint.h>

#define NROWS 8192
#define DIM 512
#define MARGIN 0.03f
#define OVF_CAP 32

typedef unsigned long long u64;
typedef uint32_t u32;
using bf16x8 = __attribute__((ext_vector_type(8))) short;
using ushort8 = __attribute__((ext_vector_type(8))) unsigned short;
using f32x4 = __attribute__((ext_vector_type(4))) float;

__device__ __forceinline__ u32 f2o(float f){
  u32 u = __float_as_uint(f);
  return (u & 0x80000000u) ? ~u : (u | 0x80000000u);
}
__device__ __forceinline__ float o2f(u32 o){
  u32 u = (o & 0x80000000u) ? (o & 0x7FFFFFFFu) : ~o;
  return __uint_as_float(u);
}
__device__ __forceinline__ unsigned short bfbits(float f){
  __hip_bfloat16 h = __float2bfloat16(f);
  return *reinterpret_cast<unsigned short*>(&h);
}
__device__ __forceinline__ unsigned short f2o16(unsigned short b){
  return (b & 0x8000u) ? (unsigned short)~b : (unsigned short)(b | 0x8000u);
}
__device__ __forceinline__ unsigned short o2b16(unsigned short o){
  return (o & 0x8000u) ? (unsigned short)(o & 0x7FFFu) : (unsigned short)~o;
}
__device__ __forceinline__ float b16f(unsigned short b){
  u32 u = (u32)b << 16;
  return __uint_as_float(u);
}
typedef __attribute__((address_space(1))) const void gvoid;
typedef __attribute__((address_space(3))) void svoid;
__device__ __forceinline__ void gll16(const void* g, void* l){
  __builtin_amdgcn_global_load_lds((gvoid*)g, (svoid*)l, 16, 0, 0);
}

// inv norms of new rows + zero the per-row overflow counters
__global__ void knorm(const float* __restrict__ x, float* __restrict__ invn,
                      u32* __restrict__ cnt){
  int row = blockIdx.x * 4 + (threadIdx.x >> 6);
  int lane = threadIdx.x & 63;
  if (threadIdx.x < 4) cnt[blockIdx.x * 4 + threadIdx.x] = 0u;
  const float4* xr = (const float4*)(x + (size_t)row * DIM);
  float s = 0.f;
  #pragma unroll
  for (int k = 0; k < 2; ++k){
    float4 v = xr[lane + 64 * k];
    s += v.x * v.x + v.y * v.y + v.z * v.z + v.w * v.w;
  }
  #pragma unroll
  for (int off = 32; off > 0; off >>= 1) s += __shfl_down(s, off);
  if (lane == 0) invn[row] = 1.0f / fmaxf(sqrtf(s), 1e-8f);
}

// fp32 -> bf16 (RNE) for both inputs; 8 elems/thread
__global__ void kconv(const float* __restrict__ a, const float* __restrict__ b,
                      unsigned short* __restrict__ abf, unsigned short* __restrict__ bbf){
  size_t i = ((size_t)blockIdx.x * 256 + threadIdx.x) * 8;
  const size_t N = (size_t)NROWS * DIM;
  const float* src; unsigned short* dst;
  if (i < N){ src = a + i; dst = abf + i; } else { src = b + (i - N); dst = bbf + (i - N); }
  float4 v0 = *(const float4*)src, v1 = *(const float4*)(src + 4);
  ushort8 w = { bfbits(v0.x), bfbits(v0.y), bfbits(v0.z), bfbits(v0.w),
                bfbits(v1.x), bfbits(v1.y), bfbits(v1.z), bfbits(v1.w) };
  *(ushort8*)dst = w;
}

// common argmax epilogue: per-row tile max + margin candidates
__device__ __forceinline__ void argmax_epilogue(
    f32x4 (&acc)[2][8], const float* __restrict__ invn,
    int m0, int n0, int ntile, int w, int c16, int g,
    u64* __restrict__ Tt, u64* __restrict__ ovf, u32* __restrict__ cnt){
  float invc[8];
  #pragma unroll
  for (int nj = 0; nj < 8; ++nj) invc[nj] = invn[n0 + nj * 16 + c16];
  #pragma unroll
  for (int mi = 0; mi < 2; ++mi){
    #pragma unroll
    for (int reg = 0; reg < 4; ++reg){
      float bv = -3.4e38f; int bj = 0;
      #pragma unroll
      for (int nj = 0; nj < 8; ++nj){       // ascending j in-thread -> strict > keeps lowest
        float v = acc[mi][nj][reg] * invc[nj];
        if (v > bv){ bv = v; bj = nj; }
      }
      int gj = n0 + bj * 16 + c16;
      u64 pk = ((u64)f2o(bv) << 32) | (u32)(~(u32)gj);
      #pragma unroll
      for (int m = 1; m < 16; m <<= 1){
        u64 o = __shfl_xor(pk, m);
        pk = pk > o ? pk : o;
      }
      int grow = m0 + w * 32 + mi * 16 + g * 4 + reg;
      if (c16 == 0) Tt[(size_t)grow * 64 + ntile] = pk;
      float thr = o2f((u32)(pk >> 32)) - MARGIN;
      int tj = (int)~((u32)pk);
      #pragma unroll
      for (int nj = 0; nj < 8; ++nj){
        float v = acc[mi][nj][reg] * invc[nj];
        int j = n0 + nj * 16 + c16;
        if (v >= thr && j != tj){
          u32 pos = atomicAdd(&cnt[grow], 1u);
          if (pos < OVF_CAP) ovf[(size_t)grow * OVF_CAP + pos] = ((u64)f2o(v) << 32) | (u32)j;
        }
      }
    }
  }
}

// fast-path GEMM: bf16 inputs, global_load_lds(16), linear LDS, BK=32, m97-style
__global__ __launch_bounds__(256) void kgemm2(
    const unsigned short* __restrict__ Abf, const unsigned short* __restrict__ Bbf,
    const float* __restrict__ invn, u64* __restrict__ Tt,
    u64* __restrict__ ovf, u32* __restrict__ cnt){
  __shared__ unsigned short As[128 * 32];   // [row][k], 64B rows -> uniform banks
  __shared__ unsigned short Bs[128 * 32];
  const int t = threadIdx.x;
  const int lane = t & 63, w = t >> 6;
  const int c16 = lane & 15, g = lane >> 4;
  // XCD-chunked swizzle: each XCD gets 512 contiguous (bm,bn) tiles
  int bid = blockIdx.x;
  int tid = (bid & 7) * 512 + (bid >> 3);
  const int bm = tid >> 6, bn = tid & 63;
  const int m0 = bm * 128, n0 = bn * 128;

  f32x4 acc[2][8];
  #pragma unroll
  for (int mi = 0; mi < 2; ++mi)
    #pragma unroll
    for (int nj = 0; nj < 8; ++nj) acc[mi][nj] = {0.f, 0.f, 0.f, 0.f};

  const int row_in = lane >> 2;   // 0..15
  const int part = lane & 3;      // 16B quarter of a 64B row

  for (int k0 = 0; k0 < DIM; k0 += 32){
    #pragma unroll
    for (int q = 0; q < 2; ++q){
      int r = w * 32 + q * 16 + row_in;
      gll16(Abf + (size_t)(m0 + r) * DIM + k0 + part * 8, (void*)&As[(w * 32 + q * 16) * 32]);
      gll16(Bbf + (size_t)(n0 + r) * DIM + k0 + part * 8, (void*)&Bs[(w * 32 + q * 16) * 32]);
    }
    __syncthreads();
    bf16x8 af[2], bfr[8];
    #pragma unroll
    for (int mi = 0; mi < 2; ++mi)
      af[mi] = *(const bf16x8*)&As[(w * 32 + mi * 16 + c16) * 32 + g * 8];
    #pragma unroll
    for (int nj = 0; nj < 8; ++nj)
      bfr[nj] = *(const bf16x8*)&Bs[(nj * 16 + c16) * 32 + g * 8];
    #pragma unroll
    for (int mi = 0; mi < 2; ++mi)
      #pragma unroll
      for (int nj = 0; nj < 8; ++nj)
        acc[mi][nj] = __builtin_amdgcn_mfma_f32_16x16x32_bf16(af[mi], bfr[nj], acc[mi][nj], 0, 0, 0);
    __syncthreads();
  }
  argmax_epilogue(acc, invn, m0, n0, bn, w, c16, g, Tt, ovf, cnt);
}

// fallback GEMM (fp32 on-the-fly conversion; proven R3 structure)
__global__ __launch_bounds__(256) void kgemm_fb(
    const float* __restrict__ A, const float* __restrict__ B,
    const float* __restrict__ invn, u64* __restrict__ Tt,
    u64* __restrict__ ovf, u32* __restrict__ cnt){
  __shared__ short As[128 * 40];
  __shared__ short Bs[128 * 40];
  const int t = threadIdx.x;
  const int lane = t & 63, w = t >> 6;
  const int c16 = lane & 15, g = lane >> 4;
  const int m0 = blockIdx.y * 128, n0 = blockIdx.x * 128;

  f32x4 acc[2][8];
  #pragma unroll
  for (int mi = 0; mi < 2; ++mi)
    #pragma unroll
    for (int nj = 0; nj < 8; ++nj) acc[mi][nj] = {0.f, 0.f, 0.f, 0.f};

  for (int k0 = 0; k0 < DIM; k0 += 32){
    #pragma unroll
    for (int it = 0; it < 2; ++it){
      int s = t + it * 256;
      int row = s >> 2, part = s & 3;
      const float4* ga = (const float4*)(A + (size_t)(m0 + row) * DIM + k0 + part * 8);
      float4 a0 = ga[0], a1 = ga[1];
      bf16x8 ha = { (short)bfbits(a0.x), (short)bfbits(a0.y), (short)bfbits(a0.z), (short)bfbits(a0.w),
                    (short)bfbits(a1.x), (short)bfbits(a1.y), (short)bfbits(a1.z), (short)bfbits(a1.w) };
      *(bf16x8*)(&As[row * 40 + part * 8]) = ha;
      const float4* gb = (const float4*)(B + (size_t)(n0 + row) * DIM + k0 + part * 8);
      float4 b0 = gb[0], b1 = gb[1];
      bf16x8 hb = { (short)bfbits(b0.x), (short)bfbits(b0.y), (short)bfbits(b0.z), (short)bfbits(b0.w),
                    (short)bfbits(b1.x), (short)bfbits(b1.y), (short)bfbits(b1.z), (short)bfbits(b1.w) };
      *(bf16x8*)(&Bs[row * 40 + part * 8]) = hb;
    }
    __syncthreads();
    bf16x8 af[2], bfr[8];
    #pragma unroll
    for (int mi = 0; mi < 2; ++mi)
      af[mi] = *(const bf16x8*)(&As[(w * 32 + mi * 16 + c16) * 40 + g * 8]);
    #pragma unroll
    for (int nj = 0; nj < 8; ++nj)
      bfr[nj] = *(const bf16x8*)(&Bs[(nj * 16 + c16) * 40 + g * 8]);
    #pragma unroll
    for (int mi = 0; mi < 2; ++mi)
      #pragma unroll
      for (int nj = 0; nj < 8; ++nj)
        acc[mi][nj] = __builtin_amdgcn_mfma_f32_16x16x32_bf16(af[mi], bfr[nj], acc[mi][nj], 0, 0, 0);
    __syncthreads();
  }
  argmax_epilogue(acc, invn, m0, n0, blockIdx.x, w, c16, g, Tt, ovf, cnt);
}

// Stage 2: one wave per row; fast path or exact fp32 dots for window candidates
__global__ __launch_bounds__(256) void kresolve(
    const float* __restrict__ A, const float* __restrict__ B,
    const float* __restrict__ invn, const u64* __restrict__ Tt,
    const u64* __restrict__ ovf, const u32* __restrict__ cnt,
    int* __restrict__ idx){
  const int r = blockIdx.x * 4 + (threadIdx.x >> 6);
  const int lane = threadIdx.x & 63;
  u64 e = Tt[(size_t)r * 64 + lane];
  u64 m = e;
  #pragma unroll
  for (int s = 1; s < 64; s <<= 1){ u64 o = __shfl_xor(m, s); m = m > o ? m : o; }
  float W = o2f((u32)(m >> 32)) - MARGIN;
  bool inw = o2f((u32)(e >> 32)) >= W;
  u64 bal = __ballot(inw);
  u32 nov_raw = cnt[r];
  int nov = nov_raw > OVF_CAP ? OVF_CAP : (int)nov_raw;
  u64 oe = (lane < nov) ? ovf[(size_t)r * OVF_CAP + lane] : 0ull;
  bool oin = (lane < nov) && (o2f((u32)(oe >> 32)) >= W);
  u64 bal2 = __ballot(oin);
  if (nov_raw <= OVF_CAP && __popcll(bal) == 1 && bal2 == 0ull){
    if (lane == 0) idx[r] = (int)~((u32)m);
    return;
  }
  const float* ar = A + (size_t)r * DIM;
  u64 best = 0ull;
  auto eval = [&](int j){
    const float* br = B + (size_t)j * DIM;
    float s = 0.f;
    for (int k = lane; k < DIM; k += 64) s = fmaf(ar[k], br[k], s);
    #pragma unroll
    for (int o = 32; o > 0; o >>= 1) s += __shfl_xor(s, o);
    s *= invn[j];
    u64 p = ((u64)f2o(s) << 32) | (u32)(~(u32)j);
    best = best > p ? best : p;
  };
  if (nov_raw > OVF_CAP){
    for (int j = 0; j < NROWS; ++j) eval(j);   // safety net, statistically unreachable
  } else {
    u64 mm = bal;
    while (mm){
      int b = __ffsll((unsigned long long)mm) - 1;
      int j = (int)~((u32)__shfl(e, b));
      eval(j);
      mm &= mm - 1;
    }
    mm = bal2;
    while (mm){
      int b = __ffsll((unsigned long long)mm) - 1;
      int j = (int)(u32)__shfl(oe, b);
      eval(j);
      mm &= mm - 1;
    }
  }
  if (lane == 0) idx[r] = (int)~((u32)best);
}

// expanded[i][:] = new[idx[i]][:]
__global__ void kexpand(const float* __restrict__ newe, const int* __restrict__ idx,
                        float* __restrict__ expd){
  int i = blockIdx.x * 2 + (threadIdx.x >> 7);
  int c = (threadIdx.x & 127) * 4;
  int j = idx[i];
  *(float4*)(expd + (size_t)i * DIM + c) =
      *(const float4*)(newe + (size_t)j * DIM + c);
}

// ---- per-column sort of OLD values as bf16 codes: 2 radix passes, 16-bit keys
__global__ __launch_bounds__(512) void ksortold(
    const float* __restrict__ olde, unsigned short* __restrict__ sortedold){
  __shared__ unsigned short keys[NROWS];          // 16 KB
  __shared__ unsigned short hist[8 * 256];        // 4 KB
  __shared__ u32 totals[256], digitbase[256];
  const int bid = blockIdx.x;
  const int c = (bid & 7) * 64 + (bid >> 3);
  const int t = threadIdx.x;
  const int lane = t & 63, w = t >> 6;            // 8 waves

  for (int e = t; e < NROWS; e += 512)
    keys[e] = f2o16(bfbits(olde[(size_t)e * DIM + c]));
  __syncthreads();

  #pragma unroll
  for (int pass = 0; pass < 2; ++pass){
    int shift = pass * 8;
    for (int i = t; i < 1024; i += 512) ((u32*)hist)[i] = 0;
    __syncthreads();
    unsigned short kreg[16]; u32 dloc[16];
    #pragma unroll
    for (int k = 0; k < 16; ++k){
      int e = w * 1024 + k * 64 + lane;
      unsigned short key = keys[e];
      kreg[k] = key;
      u32 d = ((u32)key >> shift) & 255u;
      u64 m = ~0ull;
      #pragma unroll
      for (int b = 0; b < 8; ++b){
        u64 bb = __ballot((d >> b) & 1u);
        m &= ((d >> b) & 1u) ? bb : ~bb;
      }
      int leader = __ffsll((unsigned long long)m) - 1;
      u32 rank = (u32)__popcll(m & ((1ull << lane) - 1ull));
      u32 cntg = (u32)__popcll(m);
      u32 old = 0;
      if (lane == leader){ old = hist[w * 256 + d]; hist[w * 256 + d] = (unsigned short)(old + cntg); }
      old = (u32)__shfl((int)old, leader);
      dloc[k] = (d << 16) | (old + rank);
    }
    __syncthreads();
    if (t < 256){
      u32 run = 0;
      #pragma unroll
      for (int ww = 0; ww < 8; ++ww){
        u32 v = hist[ww * 256 + t];
        hist[ww * 256 + t] = (unsigned short)run;
        run += v;
      }
      totals[t] = run;
    }
    __syncthreads();
    if (t < 64){
      u32 carry = 0;
      #pragma unroll
      for (int ch = 0; ch < 4; ++ch){
        u32 v = totals[ch * 64 + t];
        u32 inc = v;
        #pragma unroll
        for (int off = 1; off < 64; off <<= 1){
          u32 o = (u32)__shfl_up((int)inc, off);
          if (t >= off) inc += o;
        }
        digitbase[ch * 64 + t] = carry + inc - v;
        carry += (u32)__shfl((int)inc, 63);
      }
    }
    __syncthreads();
    #pragma unroll
    for (int k = 0; k < 16; ++k){
      u32 d = dloc[k] >> 16, off = dloc[k] & 0xFFFFu;
      keys[digitbase[d] + hist[w * 256 + d] + off] = kreg[k];
    }
    __syncthreads();
  }
  for (int e = t; e < NROWS; e += 512)
    sortedold[(size_t)c * NROWS + e] = o2b16(keys[e]);
}

// ---- per-column: in-place radix sort of expanded (u32 key + u16 row payload),
// then fused OT-align + 0.95*new blend. 58 KB LDS -> 2 blocks/CU.
__global__ __launch_bounds__(1024) void ksort2(
    const unsigned short* __restrict__ sortedold, const float* __restrict__ newe,
    float* expd_out){
  __shared__ u32 keys[NROWS];                     // 32 KB
  __shared__ unsigned short pay[NROWS];           // 16 KB
  __shared__ unsigned short hist[16 * 256];       // 8 KB
  __shared__ u32 totals[256], digitbase[256];     // 2 KB
  const int bid = blockIdx.x;
  const int c = (bid & 7) * 64 + (bid >> 3);
  const int t = threadIdx.x;
  const int lane = t & 63, w = t >> 6;            // 16 waves

  for (int e = t; e < NROWS; e += 1024){          // row-ascending = stability
    keys[e] = f2o(expd_out[(size_t)e * DIM + c]);
    pay[e] = (unsigned short)e;
  }
  __syncthreads();

  #pragma unroll
  for (int pass = 0; pass < 4; ++pass){
    int shift = pass * 8;
    for (int i = t; i < 2048; i += 1024) ((u32*)hist)[i] = 0;
    __syncthreads();
    u32 kreg[8], dloc[8]; unsigned short preg[8];
    #pragma unroll
    for (int k = 0; k < 8; ++k){
      int e = w * 512 + k * 64 + lane;
      u32 key = keys[e];
      preg[k] = pay[e];
      kreg[k] = key;
      u32 d = (key >> shift) & 255u;
      u64 m = ~0ull;
      #pragma unroll
      for (int b = 0; b < 8; ++b){
        u64 bb = __ballot((d >> b) & 1u);
        m &= ((d >> b) & 1u) ? bb : ~bb;
      }
      int leader = __ffsll((unsigned long long)m) - 1;
      u32 rank = (u32)__popcll(m & ((1ull << lane) - 1ull));
      u32 cntg = (u32)__popcll(m);
      u32 old = 0;
      if (lane == leader){ old = hist[w * 256 + d]; hist[w * 256 + d] = (unsigned short)(old + cntg); }
      old = (u32)__shfl((int)old, leader);
      dloc[k] = (d << 16) | (old + rank);
    }
    __syncthreads();                 // all reads done -> in-place scatter safe
    if (t < 256){
      u32 run = 0;
      #pragma unroll
      for (int ww = 0; ww < 16; ++ww){
        u32 v = hist[ww * 256 + t];
        hist[ww * 256 + t] = (unsigned short)run;
        run += v;
      }
      totals[t] = run;
    }
    __syncthreads();
    if (t < 64){
      u32 carry = 0;
      #pragma unroll
      for (int ch = 0; ch < 4; ++ch){
        u32 v = totals[ch * 64 + t];
        u32 inc = v;
        #pragma unroll
        for (int off = 1; off < 64; off <<= 1){
          u32 o = (u32)__shfl_up((int)inc, off);
          if (t >= off) inc += o;
        }
        digitbase[ch * 64 + t] = carry + inc - v;
        carry += (u32)__shfl((int)inc, 63);
      }
    }
    __syncthreads();
    #pragma unroll
    for (int k = 0; k < 8; ++k){
      u32 d = dloc[k] >> 16, off = dloc[k] & 0xFFFFu;
      u32 dst = digitbase[d] + hist[w * 256 + d] + off;
      keys[dst] = kreg[k];
      pay[dst] = preg[k];
    }
    __syncthreads();
  }

  // fused: aligned = expv + 0.05*(hsrc - expv); out = 0.95*new + 0.05*aligned
  u32 kk_[8]; unsigned short pp_[8], hb_[8];
  #pragma unroll
  for (int k = 0; k < 8; ++k){
    int e = t + k * 1024;
    kk_[k] = keys[e];
    pp_[k] = pay[e];
    hb_[k] = sortedold[(size_t)c * NROWS + e];
  }
  __syncthreads();
  #pragma unroll
  for (int k = 0; k < 8; ++k){
    float expv = o2f(kk_[k]);
    float hs = b16f(hb_[k]);
    float contrib = 0.05f * (expv + 0.05f * (hs - expv));
    keys[pp_[k]] = __float_as_uint(contrib);      // reuse keys as row-indexed stage
  }
  __syncthreads();
  #pragma unroll
  for (int k = 0; k < 8; ++k){
    int e = t + k * 1024;
    expd_out[(size_t)e * DIM + c] =
        fmaf(0.95f, newe[(size_t)e * DIM + c], __uint_as_float(keys[e]));
  }
}

// fallback per-column sort (proven R3 radix, self-contained LDS) + blend staging
template<bool HASPAY>
__device__ __forceinline__ void radix_pass_fb(
    u32* srcK, u32* srcP, u32* dstK, u32* dstP,
    u32* hist, u32* totals, u32* digitbase,
    int shift, int w, int lane, int t){
  for (int i = t; i < 4096; i += 1024) hist[i] = 0;
  __syncthreads();
  u32 kreg[8], preg[8], dloc[8];
  #pragma unroll
  for (int k = 0; k < 8; ++k){
    int e = w * 512 + k * 64 + lane;
    u32 key = srcK[e];
    if (HASPAY) preg[k] = srcP[e];
    kreg[k] = key;
    u32 d = (key >> shift) & 255u;
    u64 m = ~0ull;
    #pragma unroll
    for (int b = 0; b < 8; ++b){
      u64 bb = __ballot((d >> b) & 1u);
      m &= ((d >> b) & 1u) ? bb : ~bb;
    }
    int leader = __ffsll((unsigned long long)m) - 1;
    u32 rank = (u32)__popcll(m & ((1ull << lane) - 1ull));
    u32 cntg = (u32)__popcll(m);
    u32 old = 0;
    if (lane == leader){ old = hist[w * 256 + d]; hist[w * 256 + d] = old + cntg; }
    old = (u32)__shfl((int)old, leader);
    dloc[k] = (d << 16) | (old + rank);
  }
  __syncthreads();
  if (t < 256){
    u32 run = 0;
    #pragma unroll
    for (int ww = 0; ww < 16; ++ww){
      u32 v = hist[ww * 256 + t];
      hist[ww * 256 + t] = run;
      run += v;
    }
    totals[t] = run;
  }
  __syncthreads();
  if (t < 64){
    u32 carry = 0;
    #pragma unroll
    for (int ch = 0; ch < 4; ++ch){
      u32 v = totals[ch * 64 + t];
      u32 inc = v;
      #pragma unroll
      for (int off = 1; off < 64; off <<= 1){
        u32 o = (u32)__shfl_up((int)inc, off);
        if (t >= off) inc += o;
      }
      digitbase[ch * 64 + t] = carry + inc - v;
      carry += (u32)__shfl((int)inc, 63);
    }
  }
  __syncthreads();
  #pragma unroll
  for (int k = 0; k < 8; ++k){
    u32 d = dloc[k] >> 16, off = dloc[k] & 0xFFFFu;
    u32 dst = digitbase[d] + hist[w * 256 + d] + off;
    dstK[dst] = kreg[k];
    if (HASPAY) dstP[dst] = preg[k];
  }
  __syncthreads();
}

__global__ __launch_bounds__(1024) void ksort_fb(
    const float* __restrict__ olde, float* expd_out){
  __shared__ u32 buf0[NROWS], buf1[NROWS], pay0[NROWS], pay1[NROWS];
  __shared__ u32 hist[4096], totals[256], digitbase[256];
  const int bid = blockIdx.x;
  const int c = (bid & 7) * 64 + (bid >> 3);
  const int t = threadIdx.x;
  const int lane = t & 63, w = t >> 6;

  for (int e = t; e < NROWS; e += 1024){
    buf0[e] = f2o(expd_out[(size_t)e * DIM + c]);
    pay0[e] = (u32)e;
  }
  __syncthreads();
  radix_pass_fb<true>(buf0, pay0, buf1, pay1, hist, totals, digitbase, 0,  w, lane, t);
  radix_pass_fb<true>(buf1, pay1, buf0, pay0, hist, totals, digitbase, 8,  w, lane, t);
  radix_pass_fb<true>(buf0, pay0, buf1, pay1, hist, totals, digitbase, 16, w, lane, t);
  radix_pass_fb<true>(buf1, pay1, buf0, pay0, hist, totals, digitbase, 24, w, lane, t);
  for (int e = t; e < NROWS; e += 1024)
    buf1[e] = f2o(olde[(size_t)e * DIM + c]);
  __syncthreads();
  radix_pass_fb<false>(buf1, pay1, pay1, buf1, hist, totals, digitbase, 0,  w, lane, t);
  radix_pass_fb<false>(pay1, buf1, buf1, pay1, hist, totals, digitbase, 8,  w, lane, t);
  radix_pass_fb<false>(buf1, pay1, pay1, buf1, hist, totals, digitbase, 16, w, lane, t);
  radix_pass_fb<false>(pay1, buf1, buf1, pay1, hist, totals, digitbase, 24, w, lane, t);
  for (int e = t; e < NROWS; e += 1024){
    u32 row = pay0[e];
    float expv = o2f(buf0[e]);
    float hsrc = o2f(buf1[e]);
    float aligned = expv + 0.05f * (hsrc - expv);
    pay1[row] = __float_as_uint(0.05f * aligned);
  }
  __syncthreads();
  for (int e = t; e < NROWS; e += 1024)
    expd_out[(size_t)e * DIM + c] = __uint_as_float(pay1[e]);
}

__global__ void kfinal(const float* __restrict__ newe, float* __restrict__ out){
  size_t i = (size_t)blockIdx.x * 256 + threadIdx.x;
  float4 n4 = ((const float4*)newe)[i];
  float4 o4 = ((float4*)out)[i];
  o4.x = fmaf(0.95f, n4.x, o4.x);
  o4.y = fmaf(0.95f, n4.y, o4.y);
  o4.z = fmaf(0.95f, n4.z, o4.z);
  o4.w = fmaf(0.95f, n4.w, o4.w);
  ((float4*)out)[i] = o4;
}

extern "C" void kernel_launch(void* const* d_in, const int* in_sizes, int n_in,
                              void* d_out, int out_size, void* d_ws, size_t ws_size,
                              hipStream_t stream){
  const float* olde = (const float*)d_in[0];
  const float* newe = (const float*)d_in[1];
  float* out = (float*)d_out;
  int* idx = (int*)d_ws;                                       // [0, 32KB)
  float* invn = (float*)((char*)d_ws + 32768);                 // [32KB, 64KB)

  const size_t WS_NEED = 65536 + (size_t)512 * NROWS * 2 + 65536;  // 64KB + 8MB + pad

  if (ws_size >= WS_NEED){
    // fast path: bf16 copies in d_out; Tt/ovf/cnt in ws (dead before sortedold reuses region)
    unsigned short* Abf = (unsigned short*)d_out;                          // 8 MB
    unsigned short* Bbf = Abf + (size_t)NROWS * DIM;                       // 8 MB
    char* base = (char*)d_ws + 65536;
    u64* Tt  = (u64*)base;                                                 // 4 MB
    u64* ovf = (u64*)(base + (size_t)NROWS * 64 * 8);                      // 2 MB
    u32* cnt = (u32*)(base + (size_t)NROWS * 64 * 8 + (size_t)NROWS * OVF_CAP * 8); // 32 KB
    unsigned short* sortedold = (unsigned short*)base;                     // 8 MB (overlaps Tt/ovf/cnt)

    knorm<<<NROWS / 4, 256, 0, stream>>>(newe, invn, cnt);
    kconv<<<2 * NROWS * DIM / 8 / 256, 256, 0, stream>>>(olde, newe, Abf, Bbf);
    kgemm2<<<4096, 256, 0, stream>>>(Abf, Bbf, invn, Tt, ovf, cnt);
    kresolve<<<NROWS / 4, 256, 0, stream>>>(olde, newe, invn, Tt, ovf, cnt, idx);
    ksortold<<<DIM, 512, 0, stream>>>(olde, sortedold);
    kexpand<<<NROWS / 2, 256, 0, stream>>>(newe, idx, out);
    ksort2<<<DIM, 1024, 0, stream>>>(sortedold, newe, out);
  } else {
    // fallback: proven R3 pipeline, scratch in d_out
    u64* Tt  = (u64*)d_out;                                                // 4 MB
    u64* ovf = (u64*)((char*)d_out + (size_t)NROWS * 64 * 8);              // 2 MB
    u32* cnt = (u32*)((char*)d_out + (size_t)NROWS * 64 * 8 + (size_t)NROWS * OVF_CAP * 8);

    knorm<<<NROWS / 4, 256, 0, stream>>>(newe, invn, cnt);
    kgemm_fb<<<dim3(64, 64), 256, 0, stream>>>(olde, newe, invn, Tt, ovf, cnt);
    kresolve<<<NROWS / 4, 256, 0, stream>>>(olde, newe, invn, Tt, ovf, cnt, idx);
    kexpand<<<NROWS / 2, 256, 0, stream>>>(newe, idx, out);
    ksort_fb<<<DIM, 1024, 0, stream>>>(olde, out);
    kfinal<<<NROWS * DIM / 4 / 256, 256, 0, stream>>>(newe, out);
  }
}

// Round 5
// 284.481 us; speedup vs baseline: 3.9850x; 1.0574x over previous
//
#include <hip/hip_runtime.h>
#include <hip/hip_bf16.h>
#include <stdint.h>

#define NROWS 8192
#define DIM 512
#define MARGIN 0.03f
#define OVF_CAP 32

typedef unsigned long long u64;
typedef uint32_t u32;
using bf16x8 = __attribute__((ext_vector_type(8))) short;
using ushort8 = __attribute__((ext_vector_type(8))) unsigned short;
using f32x4 = __attribute__((ext_vector_type(4))) float;

__device__ __forceinline__ u32 f2o(float f){
  u32 u = __float_as_uint(f);
  return (u & 0x80000000u) ? ~u : (u | 0x80000000u);
}
__device__ __forceinline__ float o2f(u32 o){
  u32 u = (o & 0x80000000u) ? (o & 0x7FFFFFFFu) : ~o;
  return __uint_as_float(u);
}
__device__ __forceinline__ unsigned short bfbits(float f){
  __hip_bfloat16 h = __float2bfloat16(f);
  return *reinterpret_cast<unsigned short*>(&h);
}
__device__ __forceinline__ unsigned short f2o16(unsigned short b){
  return (b & 0x8000u) ? (unsigned short)~b : (unsigned short)(b | 0x8000u);
}
__device__ __forceinline__ unsigned short o2b16(unsigned short o){
  return (o & 0x8000u) ? (unsigned short)(o & 0x7FFFu) : (unsigned short)~o;
}
__device__ __forceinline__ float b16f(unsigned short b){
  u32 u = (u32)b << 16;
  return __uint_as_float(u);
}
typedef __attribute__((address_space(1))) const void gvoid;
typedef __attribute__((address_space(3))) void svoid;
__device__ __forceinline__ void gll16(const void* g, void* l){
  __builtin_amdgcn_global_load_lds((gvoid*)g, (svoid*)l, 16, 0, 0);
}

// inv norms of new rows + zero the per-row overflow counters
__global__ void knorm(const float* __restrict__ x, float* __restrict__ invn,
                      u32* __restrict__ cnt){
  int row = blockIdx.x * 4 + (threadIdx.x >> 6);
  int lane = threadIdx.x & 63;
  if (threadIdx.x < 4) cnt[blockIdx.x * 4 + threadIdx.x] = 0u;
  const float4* xr = (const float4*)(x + (size_t)row * DIM);
  float s = 0.f;
  #pragma unroll
  for (int k = 0; k < 2; ++k){
    float4 v = xr[lane + 64 * k];
    s += v.x * v.x + v.y * v.y + v.z * v.z + v.w * v.w;
  }
  #pragma unroll
  for (int off = 32; off > 0; off >>= 1) s += __shfl_down(s, off);
  if (lane == 0) invn[row] = 1.0f / fmaxf(sqrtf(s), 1e-8f);
}

// fp32 -> bf16 (RNE) for both inputs; 8 elems/thread
__global__ void kconv(const float* __restrict__ a, const float* __restrict__ b,
                      unsigned short* __restrict__ abf, unsigned short* __restrict__ bbf){
  size_t i = ((size_t)blockIdx.x * 256 + threadIdx.x) * 8;
  const size_t N = (size_t)NROWS * DIM;
  const float* src; unsigned short* dst;
  if (i < N){ src = a + i; dst = abf + i; } else { src = b + (i - N); dst = bbf + (i - N); }
  float4 v0 = *(const float4*)src, v1 = *(const float4*)(src + 4);
  ushort8 w = { bfbits(v0.x), bfbits(v0.y), bfbits(v0.z), bfbits(v0.w),
                bfbits(v1.x), bfbits(v1.y), bfbits(v1.z), bfbits(v1.w) };
  *(ushort8*)dst = w;
}

// common argmax epilogue: per-row tile max + margin candidates
__device__ __forceinline__ void argmax_epilogue(
    f32x4 (&acc)[2][8], const float* __restrict__ invn,
    int m0, int n0, int ntile, int w, int c16, int g,
    u64* __restrict__ Tt, u64* __restrict__ ovf, u32* __restrict__ cnt){
  float invc[8];
  #pragma unroll
  for (int nj = 0; nj < 8; ++nj) invc[nj] = invn[n0 + nj * 16 + c16];
  #pragma unroll
  for (int mi = 0; mi < 2; ++mi){
    #pragma unroll
    for (int reg = 0; reg < 4; ++reg){
      float bv = -3.4e38f; int bj = 0;
      #pragma unroll
      for (int nj = 0; nj < 8; ++nj){       // ascending j in-thread -> strict > keeps lowest
        float v = acc[mi][nj][reg] * invc[nj];
        if (v > bv){ bv = v; bj = nj; }
      }
      int gj = n0 + bj * 16 + c16;
      u64 pk = ((u64)f2o(bv) << 32) | (u32)(~(u32)gj);
      #pragma unroll
      for (int m = 1; m < 16; m <<= 1){
        u64 o = __shfl_xor(pk, m);
        pk = pk > o ? pk : o;
      }
      int grow = m0 + w * 32 + mi * 16 + g * 4 + reg;
      if (c16 == 0) Tt[(size_t)grow * 64 + ntile] = pk;
      float thr = o2f((u32)(pk >> 32)) - MARGIN;
      int tj = (int)~((u32)pk);
      #pragma unroll
      for (int nj = 0; nj < 8; ++nj){
        float v = acc[mi][nj][reg] * invc[nj];
        int j = n0 + nj * 16 + c16;
        if (v >= thr && j != tj){
          u32 pos = atomicAdd(&cnt[grow], 1u);
          if (pos < OVF_CAP) ovf[(size_t)grow * OVF_CAP + pos] = ((u64)f2o(v) << 32) | (u32)j;
        }
      }
    }
  }
}

// fast-path GEMM: bf16 inputs, global_load_lds(16), double-buffered LDS with
// stage-next-before-compute (2-phase), XOR bank swizzle, XCD-chunked 32x16
__global__ __launch_bounds__(256) void kgemm2(
    const unsigned short* __restrict__ Abf, const unsigned short* __restrict__ Bbf,
    const float* __restrict__ invn, u64* __restrict__ Tt,
    u64* __restrict__ ovf, u32* __restrict__ cnt){
  __shared__ unsigned short As[2][128 * 32];
  __shared__ unsigned short Bs[2][128 * 32];
  const int t = threadIdx.x;
  const int lane = t & 63, w = t >> 6;
  const int c16 = lane & 15, g = lane >> 4;
  // XCD chunking: 8 XCDs each own a 32(bm) x 16(bn) tile rectangle, bn-fastest
  int bid = blockIdx.x;
  int xcd = bid & 7, s = bid >> 3;
  int bm = (xcd & 1) * 32 + (s >> 4);
  int bn = (xcd >> 1) * 16 + (s & 15);
  const int m0 = bm * 128, n0 = bn * 128;

  f32x4 acc[2][8];
  #pragma unroll
  for (int mi = 0; mi < 2; ++mi)
    #pragma unroll
    for (int nj = 0; nj < 8; ++nj) acc[mi][nj] = {0.f, 0.f, 0.f, 0.f};

  const int row_in = lane >> 2;   // 0..15
  const int part = lane & 3;      // 16B quarter of a 64B row

  // stage one 128x32 K-tile of A and B into buffer `buf`; LDS linear dest,
  // inverse-swizzled global source: LDS[row][blk] = G[row][blk ^ ((row>>1)&3)]
  auto stage = [&](int buf, int k0){
    #pragma unroll
    for (int q = 0; q < 2; ++q){
      int r = w * 32 + q * 16 + row_in;
      int sc = (part ^ ((r >> 1) & 3)) * 8;
      gll16(Abf + (size_t)(m0 + r) * DIM + k0 + sc, (void*)&As[buf][(w * 32 + q * 16) * 32]);
      gll16(Bbf + (size_t)(n0 + r) * DIM + k0 + sc, (void*)&Bs[buf][(w * 32 + q * 16) * 32]);
    }
  };

  stage(0, 0);
  __syncthreads();
  int buf = 0;
  for (int kt = 0; kt < 16; ++kt){
    if (kt < 15) stage(buf ^ 1, (kt + 1) * 32);   // prefetch next tile (in flight over compute)
    bf16x8 af[2], bfr[8];
    #pragma unroll
    for (int mi = 0; mi < 2; ++mi){
      int ra = w * 32 + mi * 16 + c16;
      af[mi] = *(const bf16x8*)&As[buf][ra * 32 + (g ^ ((ra >> 1) & 3)) * 8];
    }
    #pragma unroll
    for (int nj = 0; nj < 8; ++nj){
      int rb = nj * 16 + c16;
      bfr[nj] = *(const bf16x8*)&Bs[buf][rb * 32 + (g ^ ((rb >> 1) & 3)) * 8];
    }
    #pragma unroll
    for (int mi = 0; mi < 2; ++mi)
      #pragma unroll
      for (int nj = 0; nj < 8; ++nj)
        acc[mi][nj] = __builtin_amdgcn_mfma_f32_16x16x32_bf16(af[mi], bfr[nj], acc[mi][nj], 0, 0, 0);
    __syncthreads();                               // drains prefetch + read-done for overwrite
    buf ^= 1;
  }
  argmax_epilogue(acc, invn, m0, n0, bn, w, c16, g, Tt, ovf, cnt);
}

// fallback GEMM (fp32 on-the-fly conversion; proven R3 structure)
__global__ __launch_bounds__(256) void kgemm_fb(
    const float* __restrict__ A, const float* __restrict__ B,
    const float* __restrict__ invn, u64* __restrict__ Tt,
    u64* __restrict__ ovf, u32* __restrict__ cnt){
  __shared__ short As[128 * 40];
  __shared__ short Bs[128 * 40];
  const int t = threadIdx.x;
  const int lane = t & 63, w = t >> 6;
  const int c16 = lane & 15, g = lane >> 4;
  const int m0 = blockIdx.y * 128, n0 = blockIdx.x * 128;

  f32x4 acc[2][8];
  #pragma unroll
  for (int mi = 0; mi < 2; ++mi)
    #pragma unroll
    for (int nj = 0; nj < 8; ++nj) acc[mi][nj] = {0.f, 0.f, 0.f, 0.f};

  for (int k0 = 0; k0 < DIM; k0 += 32){
    #pragma unroll
    for (int it = 0; it < 2; ++it){
      int s = t + it * 256;
      int row = s >> 2, part = s & 3;
      const float4* ga = (const float4*)(A + (size_t)(m0 + row) * DIM + k0 + part * 8);
      float4 a0 = ga[0], a1 = ga[1];
      bf16x8 ha = { (short)bfbits(a0.x), (short)bfbits(a0.y), (short)bfbits(a0.z), (short)bfbits(a0.w),
                    (short)bfbits(a1.x), (short)bfbits(a1.y), (short)bfbits(a1.z), (short)bfbits(a1.w) };
      *(bf16x8*)(&As[row * 40 + part * 8]) = ha;
      const float4* gb = (const float4*)(B + (size_t)(n0 + row) * DIM + k0 + part * 8);
      float4 b0 = gb[0], b1 = gb[1];
      bf16x8 hb = { (short)bfbits(b0.x), (short)bfbits(b0.y), (short)bfbits(b0.z), (short)bfbits(b0.w),
                    (short)bfbits(b1.x), (short)bfbits(b1.y), (short)bfbits(b1.z), (short)bfbits(b1.w) };
      *(bf16x8*)(&Bs[row * 40 + part * 8]) = hb;
    }
    __syncthreads();
    bf16x8 af[2], bfr[8];
    #pragma unroll
    for (int mi = 0; mi < 2; ++mi)
      af[mi] = *(const bf16x8*)(&As[(w * 32 + mi * 16 + c16) * 40 + g * 8]);
    #pragma unroll
    for (int nj = 0; nj < 8; ++nj)
      bfr[nj] = *(const bf16x8*)(&Bs[(nj * 16 + c16) * 40 + g * 8]);
    #pragma unroll
    for (int mi = 0; mi < 2; ++mi)
      #pragma unroll
      for (int nj = 0; nj < 8; ++nj)
        acc[mi][nj] = __builtin_amdgcn_mfma_f32_16x16x32_bf16(af[mi], bfr[nj], acc[mi][nj], 0, 0, 0);
    __syncthreads();
  }
  argmax_epilogue(acc, invn, m0, n0, blockIdx.x, w, c16, g, Tt, ovf, cnt);
}

// Stage 2: one wave per row; fast path or exact fp32 dots for window candidates
__global__ __launch_bounds__(256) void kresolve(
    const float* __restrict__ A, const float* __restrict__ B,
    const float* __restrict__ invn, const u64* __restrict__ Tt,
    const u64* __restrict__ ovf, const u32* __restrict__ cnt,
    int* __restrict__ idx){
  const int r = blockIdx.x * 4 + (threadIdx.x >> 6);
  const int lane = threadIdx.x & 63;
  u64 e = Tt[(size_t)r * 64 + lane];
  u64 m = e;
  #pragma unroll
  for (int s = 1; s < 64; s <<= 1){ u64 o = __shfl_xor(m, s); m = m > o ? m : o; }
  float W = o2f((u32)(m >> 32)) - MARGIN;
  bool inw = o2f((u32)(e >> 32)) >= W;
  u64 bal = __ballot(inw);
  u32 nov_raw = cnt[r];
  int nov = nov_raw > OVF_CAP ? OVF_CAP : (int)nov_raw;
  u64 oe = (lane < nov) ? ovf[(size_t)r * OVF_CAP + lane] : 0ull;
  bool oin = (lane < nov) && (o2f((u32)(oe >> 32)) >= W);
  u64 bal2 = __ballot(oin);
  if (nov_raw <= OVF_CAP && __popcll(bal) == 1 && bal2 == 0ull){
    if (lane == 0) idx[r] = (int)~((u32)m);
    return;
  }
  const float* ar = A + (size_t)r * DIM;
  u64 best = 0ull;
  auto eval = [&](int j){
    const float* br = B + (size_t)j * DIM;
    float s = 0.f;
    for (int k = lane; k < DIM; k += 64) s = fmaf(ar[k], br[k], s);
    #pragma unroll
    for (int o = 32; o > 0; o >>= 1) s += __shfl_xor(s, o);
    s *= invn[j];
    u64 p = ((u64)f2o(s) << 32) | (u32)(~(u32)j);
    best = best > p ? best : p;
  };
  if (nov_raw > OVF_CAP){
    for (int j = 0; j < NROWS; ++j) eval(j);   // safety net, statistically unreachable
  } else {
    u64 mm = bal;
    while (mm){
      int b = __ffsll((unsigned long long)mm) - 1;
      int j = (int)~((u32)__shfl(e, b));
      eval(j);
      mm &= mm - 1;
    }
    mm = bal2;
    while (mm){
      int b = __ffsll((unsigned long long)mm) - 1;
      int j = (int)(u32)__shfl(oe, b);
      eval(j);
      mm &= mm - 1;
    }
  }
  if (lane == 0) idx[r] = (int)~((u32)best);
}

// expanded[i][:] = new[idx[i]][:]  (fallback path only)
__global__ void kexpand(const float* __restrict__ newe, const int* __restrict__ idx,
                        float* __restrict__ expd){
  int i = blockIdx.x * 2 + (threadIdx.x >> 7);
  int c = (threadIdx.x & 127) * 4;
  int j = idx[i];
  *(float4*)(expd + (size_t)i * DIM + c) =
      *(const float4*)(newe + (size_t)j * DIM + c);
}

// ---- per-column sort of OLD values as bf16 codes: 2 radix passes, 16-bit keys
__global__ __launch_bounds__(512) void ksortold(
    const float* __restrict__ olde, unsigned short* __restrict__ sortedold){
  __shared__ unsigned short keys[NROWS];          // 16 KB
  __shared__ unsigned short hist[8 * 256];        // 4 KB
  __shared__ u32 totals[256], digitbase[256];
  const int bid = blockIdx.x;
  const int c = (bid & 7) * 64 + (bid >> 3);
  const int t = threadIdx.x;
  const int lane = t & 63, w = t >> 6;            // 8 waves

  for (int e = t; e < NROWS; e += 512)
    keys[e] = f2o16(bfbits(olde[(size_t)e * DIM + c]));
  __syncthreads();

  #pragma unroll
  for (int pass = 0; pass < 2; ++pass){
    int shift = pass * 8;
    for (int i = t; i < 1024; i += 512) ((u32*)hist)[i] = 0;
    __syncthreads();
    unsigned short kreg[16]; u32 dloc[16];
    #pragma unroll
    for (int k = 0; k < 16; ++k){
      int e = w * 1024 + k * 64 + lane;
      unsigned short key = keys[e];
      kreg[k] = key;
      u32 d = ((u32)key >> shift) & 255u;
      u64 m = ~0ull;
      #pragma unroll
      for (int b = 0; b < 8; ++b){
        u64 bb = __ballot((d >> b) & 1u);
        m &= ((d >> b) & 1u) ? bb : ~bb;
      }
      int leader = __ffsll((unsigned long long)m) - 1;
      u32 rank = (u32)__popcll(m & ((1ull << lane) - 1ull));
      u32 cntg = (u32)__popcll(m);
      u32 old = 0;
      if (lane == leader){ old = hist[w * 256 + d]; hist[w * 256 + d] = (unsigned short)(old + cntg); }
      old = (u32)__shfl((int)old, leader);
      dloc[k] = (d << 16) | (old + rank);
    }
    __syncthreads();
    if (t < 256){
      u32 run = 0;
      #pragma unroll
      for (int ww = 0; ww < 8; ++ww){
        u32 v = hist[ww * 256 + t];
        hist[ww * 256 + t] = (unsigned short)run;
        run += v;
      }
      totals[t] = run;
    }
    __syncthreads();
    if (t < 64){
      u32 carry = 0;
      #pragma unroll
      for (int ch = 0; ch < 4; ++ch){
        u32 v = totals[ch * 64 + t];
        u32 inc = v;
        #pragma unroll
        for (int off = 1; off < 64; off <<= 1){
          u32 o = (u32)__shfl_up((int)inc, off);
          if (t >= off) inc += o;
        }
        digitbase[ch * 64 + t] = carry + inc - v;
        carry += (u32)__shfl((int)inc, 63);
      }
    }
    __syncthreads();
    #pragma unroll
    for (int k = 0; k < 16; ++k){
      u32 d = dloc[k] >> 16, off = dloc[k] & 0xFFFFu;
      keys[digitbase[d] + hist[w * 256 + d] + off] = kreg[k];
    }
    __syncthreads();
  }
  for (int e = t; e < NROWS; e += 512)
    sortedold[(size_t)c * NROWS + e] = o2b16(keys[e]);
}

// ---- per-column: gather expanded as bf16 codes directly from new[idx[e]][c],
// 2-pass in-place radix sort (u16 key + u16 row payload), fused OT-align +
// 0.95*new blend. 42 KB LDS.
__global__ __launch_bounds__(1024) void ksort2(
    const unsigned short* __restrict__ sortedold, const float* __restrict__ newe,
    const int* __restrict__ idx, float* __restrict__ out){
  __shared__ u32 smem32[NROWS];                   // 32 KB: keys+pay, later contrib stage
  __shared__ unsigned short hist[16 * 256];       // 8 KB
  __shared__ u32 totals[256], digitbase[256];     // 2 KB
  unsigned short* keys = (unsigned short*)smem32;         // [0, 16KB)
  unsigned short* pay  = ((unsigned short*)smem32) + NROWS; // [16KB, 32KB)
  const int bid = blockIdx.x;
  const int c = (bid & 7) * 64 + (bid >> 3);
  const int t = threadIdx.x;
  const int lane = t & 63, w = t >> 6;            // 16 waves

  for (int e = t; e < NROWS; e += 1024){          // row-ascending = stability
    int j = idx[e];
    keys[e] = f2o16(bfbits(newe[(size_t)j * DIM + c]));
    pay[e] = (unsigned short)e;
  }
  __syncthreads();

  #pragma unroll
  for (int pass = 0; pass < 2; ++pass){
    int shift = pass * 8;
    for (int i = t; i < 2048; i += 1024) ((u32*)hist)[i] = 0;
    __syncthreads();
    unsigned short kreg[8], preg[8]; u32 dloc[8];
    #pragma unroll
    for (int k = 0; k < 8; ++k){
      int e = w * 512 + k * 64 + lane;
      unsigned short key = keys[e];
      preg[k] = pay[e];
      kreg[k] = key;
      u32 d = ((u32)key >> shift) & 255u;
      u64 m = ~0ull;
      #pragma unroll
      for (int b = 0; b < 8; ++b){
        u64 bb = __ballot((d >> b) & 1u);
        m &= ((d >> b) & 1u) ? bb : ~bb;
      }
      int leader = __ffsll((unsigned long long)m) - 1;
      u32 rank = (u32)__popcll(m & ((1ull << lane) - 1ull));
      u32 cntg = (u32)__popcll(m);
      u32 old = 0;
      if (lane == leader){ old = hist[w * 256 + d]; hist[w * 256 + d] = (unsigned short)(old + cntg); }
      old = (u32)__shfl((int)old, leader);
      dloc[k] = (d << 16) | (old + rank);
    }
    __syncthreads();                 // all reads done -> in-place scatter safe
    if (t < 256){
      u32 run = 0;
      #pragma unroll
      for (int ww = 0; ww < 16; ++ww){
        u32 v = hist[ww * 256 + t];
        hist[ww * 256 + t] = (unsigned short)run;
        run += v;
      }
      totals[t] = run;
    }
    __syncthreads();
    if (t < 64){
      u32 carry = 0;
      #pragma unroll
      for (int ch = 0; ch < 4; ++ch){
        u32 v = totals[ch * 64 + t];
        u32 inc = v;
        #pragma unroll
        for (int off = 1; off < 64; off <<= 1){
          u32 o = (u32)__shfl_up((int)inc, off);
          if (t >= off) inc += o;
        }
        digitbase[ch * 64 + t] = carry + inc - v;
        carry += (u32)__shfl((int)inc, 63);
      }
    }
    __syncthreads();
    #pragma unroll
    for (int k = 0; k < 8; ++k){
      u32 d = dloc[k] >> 16, off = dloc[k] & 0xFFFFu;
      u32 dst = digitbase[d] + hist[w * 256 + d] + off;
      keys[dst] = kreg[k];
      pay[dst] = preg[k];
    }
    __syncthreads();
  }

  // fused: aligned = 0.95*expv + 0.05*hsrc; out = 0.95*new + 0.05*aligned
  unsigned short kv_[8], pp_[8], hb_[8];
  #pragma unroll
  for (int k = 0; k < 8; ++k){
    int e = t + k * 1024;
    kv_[k] = keys[e];
    pp_[k] = pay[e];
    hb_[k] = sortedold[(size_t)c * NROWS + e];
  }
  __syncthreads();
  #pragma unroll
  for (int k = 0; k < 8; ++k){
    float expv = b16f(o2b16(kv_[k]));
    float hs = b16f(hb_[k]);
    float contrib = 0.05f * fmaf(0.95f, expv, 0.05f * hs);
    smem32[pp_[k]] = __float_as_uint(contrib);    // row-indexed stage (overwrites keys/pay)
  }
  __syncthreads();
  #pragma unroll
  for (int k = 0; k < 8; ++k){
    int e = t + k * 1024;
    out[(size_t)e * DIM + c] =
        fmaf(0.95f, newe[(size_t)e * DIM + c], __uint_as_float(smem32[e]));
  }
}

// fallback per-column sort (proven R3 radix, self-contained LDS) + blend staging
template<bool HASPAY>
__device__ __forceinline__ void radix_pass_fb(
    u32* srcK, u32* srcP, u32* dstK, u32* dstP,
    u32* hist, u32* totals, u32* digitbase,
    int shift, int w, int lane, int t){
  for (int i = t; i < 4096; i += 1024) hist[i] = 0;
  __syncthreads();
  u32 kreg[8], preg[8], dloc[8];
  #pragma unroll
  for (int k = 0; k < 8; ++k){
    int e = w * 512 + k * 64 + lane;
    u32 key = srcK[e];
    if (HASPAY) preg[k] = srcP[e];
    kreg[k] = key;
    u32 d = (key >> shift) & 255u;
    u64 m = ~0ull;
    #pragma unroll
    for (int b = 0; b < 8; ++b){
      u64 bb = __ballot((d >> b) & 1u);
      m &= ((d >> b) & 1u) ? bb : ~bb;
    }
    int leader = __ffsll((unsigned long long)m) - 1;
    u32 rank = (u32)__popcll(m & ((1ull << lane) - 1ull));
    u32 cntg = (u32)__popcll(m);
    u32 old = 0;
    if (lane == leader){ old = hist[w * 256 + d]; hist[w * 256 + d] = old + cntg; }
    old = (u32)__shfl((int)old, leader);
    dloc[k] = (d << 16) | (old + rank);
  }
  __syncthreads();
  if (t < 256){
    u32 run = 0;
    #pragma unroll
    for (int ww = 0; ww < 16; ++ww){
      u32 v = hist[ww * 256 + t];
      hist[ww * 256 + t] = run;
      run += v;
    }
    totals[t] = run;
  }
  __syncthreads();
  if (t < 64){
    u32 carry = 0;
    #pragma unroll
    for (int ch = 0; ch < 4; ++ch){
      u32 v = totals[ch * 64 + t];
      u32 inc = v;
      #pragma unroll
      for (int off = 1; off < 64; off <<= 1){
        u32 o = (u32)__shfl_up((int)inc, off);
        if (t >= off) inc += o;
      }
      digitbase[ch * 64 + t] = carry + inc - v;
      carry += (u32)__shfl((int)inc, 63);
    }
  }
  __syncthreads();
  #pragma unroll
  for (int k = 0; k < 8; ++k){
    u32 d = dloc[k] >> 16, off = dloc[k] & 0xFFFFu;
    u32 dst = digitbase[d] + hist[w * 256 + d] + off;
    dstK[dst] = kreg[k];
    if (HASPAY) dstP[dst] = preg[k];
  }
  __syncthreads();
}

__global__ __launch_bounds__(1024) void ksort_fb(
    const float* __restrict__ olde, float* expd_out){
  __shared__ u32 buf0[NROWS], buf1[NROWS], pay0[NROWS], pay1[NROWS];
  __shared__ u32 hist[4096], totals[256], digitbase[256];
  const int bid = blockIdx.x;
  const int c = (bid & 7) * 64 + (bid >> 3);
  const int t = threadIdx.x;
  const int lane = t & 63, w = t >> 6;

  for (int e = t; e < NROWS; e += 1024){
    buf0[e] = f2o(expd_out[(size_t)e * DIM + c]);
    pay0[e] = (u32)e;
  }
  __syncthreads();
  radix_pass_fb<true>(buf0, pay0, buf1, pay1, hist, totals, digitbase, 0,  w, lane, t);
  radix_pass_fb<true>(buf1, pay1, buf0, pay0, hist, totals, digitbase, 8,  w, lane, t);
  radix_pass_fb<true>(buf0, pay0, buf1, pay1, hist, totals, digitbase, 16, w, lane, t);
  radix_pass_fb<true>(buf1, pay1, buf0, pay0, hist, totals, digitbase, 24, w, lane, t);
  for (int e = t; e < NROWS; e += 1024)
    buf1[e] = f2o(olde[(size_t)e * DIM + c]);
  __syncthreads();
  radix_pass_fb<false>(buf1, pay1, pay1, buf1, hist, totals, digitbase, 0,  w, lane, t);
  radix_pass_fb<false>(pay1, buf1, buf1, pay1, hist, totals, digitbase, 8,  w, lane, t);
  radix_pass_fb<false>(buf1, pay1, pay1, buf1, hist, totals, digitbase, 16, w, lane, t);
  radix_pass_fb<false>(pay1, buf1, buf1, pay1, hist, totals, digitbase, 24, w, lane, t);
  for (int e = t; e < NROWS; e += 1024){
    u32 row = pay0[e];
    float expv = o2f(buf0[e]);
    float hsrc = o2f(buf1[e]);
    float aligned = expv + 0.05f * (hsrc - expv);
    pay1[row] = __float_as_uint(0.05f * aligned);
  }
  __syncthreads();
  for (int e = t; e < NROWS; e += 1024)
    expd_out[(size_t)e * DIM + c] = __uint_as_float(pay1[e]);
}

__global__ void kfinal(const float* __restrict__ newe, float* __restrict__ out){
  size_t i = (size_t)blockIdx.x * 256 + threadIdx.x;
  float4 n4 = ((const float4*)newe)[i];
  float4 o4 = ((float4*)out)[i];
  o4.x = fmaf(0.95f, n4.x, o4.x);
  o4.y = fmaf(0.95f, n4.y, o4.y);
  o4.z = fmaf(0.95f, n4.z, o4.z);
  o4.w = fmaf(0.95f, n4.w, o4.w);
  ((float4*)out)[i] = o4;
}

extern "C" void kernel_launch(void* const* d_in, const int* in_sizes, int n_in,
                              void* d_out, int out_size, void* d_ws, size_t ws_size,
                              hipStream_t stream){
  const float* olde = (const float*)d_in[0];
  const float* newe = (const float*)d_in[1];
  float* out = (float*)d_out;
  int* idx = (int*)d_ws;                                       // [0, 32KB)
  float* invn = (float*)((char*)d_ws + 32768);                 // [32KB, 64KB)

  const size_t WS_NEED = 65536 + (size_t)512 * NROWS * 2 + 65536;  // 64KB + 8MB + pad

  if (ws_size >= WS_NEED){
    // fast path: bf16 copies in d_out (dead after kgemm2); Tt/ovf/cnt in ws
    // (dead after kresolve, region then reused by sortedold)
    unsigned short* Abf = (unsigned short*)d_out;                          // 8 MB
    unsigned short* Bbf = Abf + (size_t)NROWS * DIM;                       // 8 MB
    char* base = (char*)d_ws + 65536;
    u64* Tt  = (u64*)base;                                                 // 4 MB
    u64* ovf = (u64*)(base + (size_t)NROWS * 64 * 8);                      // 2 MB
    u32* cnt = (u32*)(base + (size_t)NROWS * 64 * 8 + (size_t)NROWS * OVF_CAP * 8); // 32 KB
    unsigned short* sortedold = (unsigned short*)base;                     // 8 MB (overlaps Tt/ovf/cnt)

    knorm<<<NROWS / 4, 256, 0, stream>>>(newe, invn, cnt);
    kconv<<<2 * NROWS * DIM / 8 / 256, 256, 0, stream>>>(olde, newe, Abf, Bbf);
    kgemm2<<<4096, 256, 0, stream>>>(Abf, Bbf, invn, Tt, ovf, cnt);
    kresolve<<<NROWS / 4, 256, 0, stream>>>(olde, newe, invn, Tt, ovf, cnt, idx);
    ksortold<<<DIM, 512, 0, stream>>>(olde, sortedold);
    ksort2<<<DIM, 1024, 0, stream>>>(sortedold, newe, idx, out);
  } else {
    // fallback: proven R3 pipeline, scratch in d_out
    u64* Tt  = (u64*)d_out;                                                // 4 MB
    u64* ovf = (u64*)((char*)d_out + (size_t)NROWS * 64 * 8);              // 2 MB
    u32* cnt = (u32*)((char*)d_out + (size_t)NROWS * 64 * 8 + (size_t)NROWS * OVF_CAP * 8);

    knorm<<<NROWS / 4, 256, 0, stream>>>(newe, invn, cnt);
    kgemm_fb<<<dim3(64, 64), 256, 0, stream>>>(olde, newe, invn, Tt, ovf, cnt);
    kresolve<<<NROWS / 4, 256, 0, stream>>>(olde, newe, invn, Tt, ovf, cnt, idx);
    kexpand<<<NROWS / 2, 256, 0, stream>>>(newe, idx, out);
    ksort_fb<<<DIM, 1024, 0, stream>>>(olde, out);
    kfinal<<<NROWS * DIM / 4 / 256, 256, 0, stream>>>(newe, out);
  }
}

// Round 6
// 248.296 us; speedup vs baseline: 4.5657x; 1.1457x over previous
//
#include <hip/hip_runtime.h>
#include <hip/hip_bf16.h>
#include <stdint.h>

#define NROWS 8192
#define DIM 512
#define MARGIN 0.03f
#define OVF_CAP 32

typedef unsigned long long u64;
typedef uint32_t u32;
using bf16x8 = __attribute__((ext_vector_type(8))) short;
using ushort8 = __attribute__((ext_vector_type(8))) unsigned short;
using f32x4 = __attribute__((ext_vector_type(4))) float;

__device__ __forceinline__ u32 f2o(float f){
  u32 u = __float_as_uint(f);
  return (u & 0x80000000u) ? ~u : (u | 0x80000000u);
}
__device__ __forceinline__ float o2f(u32 o){
  u32 u = (o & 0x80000000u) ? (o & 0x7FFFFFFFu) : ~o;
  return __uint_as_float(u);
}
__device__ __forceinline__ unsigned short bfbits(float f){
  __hip_bfloat16 h = __float2bfloat16(f);
  return *reinterpret_cast<unsigned short*>(&h);
}
__device__ __forceinline__ unsigned short f2o16(unsigned short b){
  return (b & 0x8000u) ? (unsigned short)~b : (unsigned short)(b | 0x8000u);
}
__device__ __forceinline__ unsigned short o2b16(unsigned short o){
  return (o & 0x8000u) ? (unsigned short)(o & 0x7FFFu) : (unsigned short)~o;
}
__device__ __forceinline__ float b16f(unsigned short b){
  u32 u = (u32)b << 16;
  return __uint_as_float(u);
}
typedef __attribute__((address_space(1))) const void gvoid;
typedef __attribute__((address_space(3))) void svoid;
__device__ __forceinline__ void gll16(const void* g, void* l){
  __builtin_amdgcn_global_load_lds((gvoid*)g, (svoid*)l, 16, 0, 0);
}

// fused fp32->bf16 conversion (both inputs) + inv-norms of new rows + cnt zero.
// 4 waves/block, one wave per 512-elem row.
__global__ void kconvnorm(const float* __restrict__ olde, const float* __restrict__ newe,
                          unsigned short* __restrict__ abf, unsigned short* __restrict__ bbf,
                          float* __restrict__ invn, u32* __restrict__ cnt){
  int row = blockIdx.x * 4 + (threadIdx.x >> 6);    // 0..16383
  int lane = threadIdx.x & 63;
  if (blockIdx.x < 32) cnt[blockIdx.x * 256 + threadIdx.x] = 0u;
  bool isnew = row >= NROWS;
  int r = isnew ? row - NROWS : row;
  const float* src = (isnew ? newe : olde) + (size_t)r * DIM + lane * 8;
  unsigned short* dst = (isnew ? bbf : abf) + (size_t)r * DIM + lane * 8;
  float4 v0 = *(const float4*)src, v1 = *(const float4*)(src + 4);
  ushort8 wv = { bfbits(v0.x), bfbits(v0.y), bfbits(v0.z), bfbits(v0.w),
                 bfbits(v1.x), bfbits(v1.y), bfbits(v1.z), bfbits(v1.w) };
  *(ushort8*)dst = wv;
  if (isnew){
    float s = v0.x*v0.x + v0.y*v0.y + v0.z*v0.z + v0.w*v0.w
            + v1.x*v1.x + v1.y*v1.y + v1.z*v1.z + v1.w*v1.w;
    #pragma unroll
    for (int off = 32; off > 0; off >>= 1) s += __shfl_down(s, off);
    if (lane == 0) invn[r] = 1.0f / fmaxf(sqrtf(s), 1e-8f);
  }
}

// inv norms only (fallback path)
__global__ void knorm(const float* __restrict__ x, float* __restrict__ invn,
                      u32* __restrict__ cnt){
  int row = blockIdx.x * 4 + (threadIdx.x >> 6);
  int lane = threadIdx.x & 63;
  if (threadIdx.x < 4) cnt[blockIdx.x * 4 + threadIdx.x] = 0u;
  const float4* xr = (const float4*)(x + (size_t)row * DIM);
  float s = 0.f;
  #pragma unroll
  for (int k = 0; k < 2; ++k){
    float4 v = xr[lane + 64 * k];
    s += v.x * v.x + v.y * v.y + v.z * v.z + v.w * v.w;
  }
  #pragma unroll
  for (int off = 32; off > 0; off >>= 1) s += __shfl_down(s, off);
  if (lane == 0) invn[row] = 1.0f / fmaxf(sqrtf(s), 1e-8f);
}

// common argmax epilogue: per-row tile max (over this wave's 128 cols) + margin
// candidates. wr = wave row-group (rows wr*32+...), n0w = wave's first col,
// ntile = global 128-col tile index.
__device__ __forceinline__ void argmax_epilogue(
    f32x4 (&acc)[2][8], const float* __restrict__ invn,
    int m0, int n0w, int ntile, int wr, int c16, int g,
    u64* __restrict__ Tt, u64* __restrict__ ovf, u32* __restrict__ cnt){
  float invc[8];
  #pragma unroll
  for (int nj = 0; nj < 8; ++nj) invc[nj] = invn[n0w + nj * 16 + c16];
  #pragma unroll
  for (int mi = 0; mi < 2; ++mi){
    #pragma unroll
    for (int reg = 0; reg < 4; ++reg){
      float bv = -3.4e38f; int bj = 0;
      #pragma unroll
      for (int nj = 0; nj < 8; ++nj){       // ascending j in-thread -> strict > keeps lowest
        float v = acc[mi][nj][reg] * invc[nj];
        if (v > bv){ bv = v; bj = nj; }
      }
      int gj = n0w + bj * 16 + c16;
      u64 pk = ((u64)f2o(bv) << 32) | (u32)(~(u32)gj);
      #pragma unroll
      for (int m = 1; m < 16; m <<= 1){     // reduce across the 16 cols of this row
        u64 o = __shfl_xor(pk, m);
        pk = pk > o ? pk : o;
      }
      int grow = m0 + wr * 32 + mi * 16 + g * 4 + reg;
      if (c16 == 0) Tt[(size_t)grow * 64 + ntile] = pk;
      float thr = o2f((u32)(pk >> 32)) - MARGIN;
      int tj = (int)~((u32)pk);
      #pragma unroll
      for (int nj = 0; nj < 8; ++nj){
        float v = acc[mi][nj][reg] * invc[nj];
        int j = n0w + nj * 16 + c16;
        if (v >= thr && j != tj){
          u32 pos = atomicAdd(&cnt[grow], 1u);
          if (pos < OVF_CAP) ovf[(size_t)grow * OVF_CAP + pos] = ((u64)f2o(v) << 32) | (u32)j;
        }
      }
    }
  }
}

// fast-path GEMM: 128x256 tile, 8 waves, BK=32, single-buffer stage->sync->
// compute->sync, zero-conflict XOR swizzle (both sides), XCD rectangle.
__global__ __launch_bounds__(512) void kgemm2(
    const unsigned short* __restrict__ Abf, const unsigned short* __restrict__ Bbf,
    const float* __restrict__ invn, u64* __restrict__ Tt,
    u64* __restrict__ ovf, u32* __restrict__ cnt){
  __shared__ unsigned short As[128 * 32];   // 8 KB
  __shared__ unsigned short Bs[256 * 32];   // 16 KB
  const int t = threadIdx.x;
  const int lane = t & 63, w = t >> 6;      // 8 waves
  const int c16 = lane & 15, g = lane >> 4;
  const int wr = w >> 1, wc = w & 1;        // wave: rows wr*32.., cols wc*128..
  // XCD rectangle: grid 64(bm) x 32(bn); each XCD owns 32bm x 8bn, bn-fastest
  int bid = blockIdx.x;
  int xcd = bid & 7, s = bid >> 3;          // s 0..255
  int bm = (xcd & 1) * 32 + (s >> 3);       // 0..63
  int bn = (xcd >> 1) * 8 + (s & 7);        // 0..31
  const int m0 = bm * 128, n0 = bn * 256;

  f32x4 acc[2][8];
  #pragma unroll
  for (int mi = 0; mi < 2; ++mi)
    #pragma unroll
    for (int nj = 0; nj < 8; ++nj) acc[mi][nj] = {0.f, 0.f, 0.f, 0.f};

  const int srow = t >> 2;    // 0..127
  const int part = t & 3;     // 16B quarter of a 64B row

  for (int k0 = 0; k0 < DIM; k0 += 32){
    // A: 8 KB (one gll16/thread); LDS linear dest, inverse-swizzled global src
    {
      int sc = (part ^ ((srow >> 1) & 3)) * 8;
      gll16(Abf + (size_t)(m0 + srow) * DIM + k0 + sc, (void*)&As[(w * 16) * 32]);
    }
    // B: 16 KB (two gll16/thread)
    {
      int sc = (part ^ ((srow >> 1) & 3)) * 8;
      gll16(Bbf + (size_t)(n0 + srow) * DIM + k0 + sc, (void*)&Bs[(w * 16) * 32]);
      int r2 = srow + 128;
      int sc2 = (part ^ ((r2 >> 1) & 3)) * 8;
      gll16(Bbf + (size_t)(n0 + r2) * DIM + k0 + sc2, (void*)&Bs[(128 + w * 16) * 32]);
    }
    __syncthreads();
    bf16x8 af[2], bfr[8];
    #pragma unroll
    for (int mi = 0; mi < 2; ++mi){
      int ra = wr * 32 + mi * 16 + c16;
      af[mi] = *(const bf16x8*)&As[ra * 32 + (g ^ ((ra >> 1) & 3)) * 8];
    }
    #pragma unroll
    for (int nj = 0; nj < 8; ++nj){
      int rb = wc * 128 + nj * 16 + c16;
      bfr[nj] = *(const bf16x8*)&Bs[rb * 32 + (g ^ ((rb >> 1) & 3)) * 8];
    }
    #pragma unroll
    for (int mi = 0; mi < 2; ++mi)
      #pragma unroll
      for (int nj = 0; nj < 8; ++nj)
        acc[mi][nj] = __builtin_amdgcn_mfma_f32_16x16x32_bf16(af[mi], bfr[nj], acc[mi][nj], 0, 0, 0);
    __syncthreads();
  }
  argmax_epilogue(acc, invn, m0, n0 + wc * 128, bn * 2 + wc, wr, c16, g, Tt, ovf, cnt);
}

// fallback GEMM (fp32 on-the-fly conversion; proven R3 structure)
__global__ __launch_bounds__(256) void kgemm_fb(
    const float* __restrict__ A, const float* __restrict__ B,
    const float* __restrict__ invn, u64* __restrict__ Tt,
    u64* __restrict__ ovf, u32* __restrict__ cnt){
  __shared__ short As[128 * 40];
  __shared__ short Bs[128 * 40];
  const int t = threadIdx.x;
  const int lane = t & 63, w = t >> 6;
  const int c16 = lane & 15, g = lane >> 4;
  const int m0 = blockIdx.y * 128, n0 = blockIdx.x * 128;

  f32x4 acc[2][8];
  #pragma unroll
  for (int mi = 0; mi < 2; ++mi)
    #pragma unroll
    for (int nj = 0; nj < 8; ++nj) acc[mi][nj] = {0.f, 0.f, 0.f, 0.f};

  for (int k0 = 0; k0 < DIM; k0 += 32){
    #pragma unroll
    for (int it = 0; it < 2; ++it){
      int s = t + it * 256;
      int row = s >> 2, part = s & 3;
      const float4* ga = (const float4*)(A + (size_t)(m0 + row) * DIM + k0 + part * 8);
      float4 a0 = ga[0], a1 = ga[1];
      bf16x8 ha = { (short)bfbits(a0.x), (short)bfbits(a0.y), (short)bfbits(a0.z), (short)bfbits(a0.w),
                    (short)bfbits(a1.x), (short)bfbits(a1.y), (short)bfbits(a1.z), (short)bfbits(a1.w) };
      *(bf16x8*)(&As[row * 40 + part * 8]) = ha;
      const float4* gb = (const float4*)(B + (size_t)(n0 + row) * DIM + k0 + part * 8);
      float4 b0 = gb[0], b1 = gb[1];
      bf16x8 hb = { (short)bfbits(b0.x), (short)bfbits(b0.y), (short)bfbits(b0.z), (short)bfbits(b0.w),
                    (short)bfbits(b1.x), (short)bfbits(b1.y), (short)bfbits(b1.z), (short)bfbits(b1.w) };
      *(bf16x8*)(&Bs[row * 40 + part * 8]) = hb;
    }
    __syncthreads();
    bf16x8 af[2], bfr[8];
    #pragma unroll
    for (int mi = 0; mi < 2; ++mi)
      af[mi] = *(const bf16x8*)(&As[(w * 32 + mi * 16 + c16) * 40 + g * 8]);
    #pragma unroll
    for (int nj = 0; nj < 8; ++nj)
      bfr[nj] = *(const bf16x8*)(&Bs[(nj * 16 + c16) * 40 + g * 8]);
    #pragma unroll
    for (int mi = 0; mi < 2; ++mi)
      #pragma unroll
      for (int nj = 0; nj < 8; ++nj)
        acc[mi][nj] = __builtin_amdgcn_mfma_f32_16x16x32_bf16(af[mi], bfr[nj], acc[mi][nj], 0, 0, 0);
    __syncthreads();
  }
  argmax_epilogue(acc, invn, m0, n0, blockIdx.x, w, c16, g, Tt, ovf, cnt);
}

// Stage 2: one wave per row; fast path or exact fp32 dots for window candidates
__global__ __launch_bounds__(256) void kresolve(
    const float* __restrict__ A, const float* __restrict__ B,
    const float* __restrict__ invn, const u64* __restrict__ Tt,
    const u64* __restrict__ ovf, const u32* __restrict__ cnt,
    int* __restrict__ idx){
  const int r = blockIdx.x * 4 + (threadIdx.x >> 6);
  const int lane = threadIdx.x & 63;
  u64 e = Tt[(size_t)r * 64 + lane];
  u64 m = e;
  #pragma unroll
  for (int s = 1; s < 64; s <<= 1){ u64 o = __shfl_xor(m, s); m = m > o ? m : o; }
  float W = o2f((u32)(m >> 32)) - MARGIN;
  bool inw = o2f((u32)(e >> 32)) >= W;
  u64 bal = __ballot(inw);
  u32 nov_raw = cnt[r];
  int nov = nov_raw > OVF_CAP ? OVF_CAP : (int)nov_raw;
  u64 oe = (lane < nov) ? ovf[(size_t)r * OVF_CAP + lane] : 0ull;
  bool oin = (lane < nov) && (o2f((u32)(oe >> 32)) >= W);
  u64 bal2 = __ballot(oin);
  if (nov_raw <= OVF_CAP && __popcll(bal) == 1 && bal2 == 0ull){
    if (lane == 0) idx[r] = (int)~((u32)m);
    return;
  }
  const float* ar = A + (size_t)r * DIM;
  u64 best = 0ull;
  auto eval = [&](int j){
    const float* br = B + (size_t)j * DIM;
    float s = 0.f;
    for (int k = lane; k < DIM; k += 64) s = fmaf(ar[k], br[k], s);
    #pragma unroll
    for (int o = 32; o > 0; o >>= 1) s += __shfl_xor(s, o);
    s *= invn[j];
    u64 p = ((u64)f2o(s) << 32) | (u32)(~(u32)j);
    best = best > p ? best : p;
  };
  if (nov_raw > OVF_CAP){
    for (int j = 0; j < NROWS; ++j) eval(j);   // safety net, statistically unreachable
  } else {
    u64 mm = bal;
    while (mm){
      int b = __ffsll((unsigned long long)mm) - 1;
      int j = (int)~((u32)__shfl(e, b));
      eval(j);
      mm &= mm - 1;
    }
    mm = bal2;
    while (mm){
      int b = __ffsll((unsigned long long)mm) - 1;
      int j = (int)(u32)__shfl(oe, b);
      eval(j);
      mm &= mm - 1;
    }
  }
  if (lane == 0) idx[r] = (int)~((u32)best);
}

// expanded[i][:] = new[idx[i]][:]  (fallback path only)
__global__ void kexpand(const float* __restrict__ newe, const int* __restrict__ idx,
                        float* __restrict__ expd){
  int i = blockIdx.x * 2 + (threadIdx.x >> 7);
  int c = (threadIdx.x & 127) * 4;
  int j = idx[i];
  *(float4*)(expd + (size_t)i * DIM + c) =
      *(const float4*)(newe + (size_t)j * DIM + c);
}

// one in-place stable radix pass over 8192 u16 keys (+optional u16 payload),
// 16 waves, 8 elems/thread in (k,lane) order
template<bool HASPAY>
__device__ __forceinline__ void sortpass16(
    unsigned short* keys, unsigned short* pay,
    unsigned short* hist, u32* totals, u32* digitbase,
    int shift, int w, int lane, int t){
  for (int i = t; i < 2048; i += 1024) ((u32*)hist)[i] = 0;
  __syncthreads();
  unsigned short kreg[8], preg[8]; u32 dloc[8];
  #pragma unroll
  for (int k = 0; k < 8; ++k){
    int e = w * 512 + k * 64 + lane;
    unsigned short key = keys[e];
    if (HASPAY) preg[k] = pay[e];
    kreg[k] = key;
    u32 d = ((u32)key >> shift) & 255u;
    u64 m = ~0ull;
    #pragma unroll
    for (int b = 0; b < 8; ++b){
      u64 bb = __ballot((d >> b) & 1u);
      m &= ((d >> b) & 1u) ? bb : ~bb;
    }
    int leader = __ffsll((unsigned long long)m) - 1;
    u32 rank = (u32)__popcll(m & ((1ull << lane) - 1ull));
    u32 cntg = (u32)__popcll(m);
    u32 old = 0;
    if (lane == leader){ old = hist[w * 256 + d]; hist[w * 256 + d] = (unsigned short)(old + cntg); }
    old = (u32)__shfl((int)old, leader);
    dloc[k] = (d << 16) | (old + rank);
  }
  __syncthreads();                 // all reads done -> in-place scatter safe
  if (t < 256){
    u32 run = 0;
    #pragma unroll
    for (int ww = 0; ww < 16; ++ww){
      u32 v = hist[ww * 256 + t];
      hist[ww * 256 + t] = (unsigned short)run;
      run += v;
    }
    totals[t] = run;
  }
  __syncthreads();
  if (t < 64){
    u32 carry = 0;
    #pragma unroll
    for (int ch = 0; ch < 4; ++ch){
      u32 v = totals[ch * 64 + t];
      u32 inc = v;
      #pragma unroll
      for (int off = 1; off < 64; off <<= 1){
        u32 o = (u32)__shfl_up((int)inc, off);
        if (t >= off) inc += o;
      }
      digitbase[ch * 64 + t] = carry + inc - v;
      carry += (u32)__shfl((int)inc, 63);
    }
  }
  __syncthreads();
  #pragma unroll
  for (int k = 0; k < 8; ++k){
    u32 d = dloc[k] >> 16, off = dloc[k] & 0xFFFFu;
    u32 dst = digitbase[d] + hist[w * 256 + d] + off;
    keys[dst] = kreg[k];
    if (HASPAY) pay[dst] = preg[k];
  }
  __syncthreads();
}

// merged per-column pipeline: sort old col (bf16 codes, in LDS), gather+sort
// expanded (bf16 codes + row payload), fused OT-align + 0.95*new blend.
// 58 KB LDS -> 2 blocks/CU; 512 blocks = fully resident.
__global__ __launch_bounds__(1024) void ksort2(
    const float* __restrict__ olde, const float* __restrict__ newe,
    const int* __restrict__ idx, float* __restrict__ out){
  __shared__ u32 smem32[NROWS];                   // 32 KB: keysE+pay, later contrib
  __shared__ unsigned short keysO[NROWS];         // 16 KB: sorted old codes
  __shared__ unsigned short hist[16 * 256];       // 8 KB
  __shared__ u32 totals[256], digitbase[256];     // 2 KB
  unsigned short* keys = (unsigned short*)smem32;
  unsigned short* pay  = ((unsigned short*)smem32) + NROWS;
  const int bid = blockIdx.x;
  const int c = (bid & 7) * 64 + (bid >> 3);      // XCD-grouped column
  const int t = threadIdx.x;
  const int lane = t & 63, w = t >> 6;            // 16 waves

  // phase 1: old column -> codes, 2-pass keys-only sort (stays in LDS)
  for (int e = t; e < NROWS; e += 1024)
    keysO[e] = f2o16(bfbits(olde[(size_t)e * DIM + c]));
  __syncthreads();
  sortpass16<false>(keysO, nullptr, hist, totals, digitbase, 0, w, lane, t);
  sortpass16<false>(keysO, nullptr, hist, totals, digitbase, 8, w, lane, t);

  // phase 2: gather expanded codes + row payload, 2-pass stable sort
  for (int e = t; e < NROWS; e += 1024){          // row-ascending = stability
    int j = idx[e];
    keys[e] = f2o16(bfbits(newe[(size_t)j * DIM + c]));
    pay[e] = (unsigned short)e;
  }
  __syncthreads();
  sortpass16<true>(keys, pay, hist, totals, digitbase, 0, w, lane, t);
  sortpass16<true>(keys, pay, hist, totals, digitbase, 8, w, lane, t);

  // phase 3: aligned = 0.95*expv + 0.05*hsrc; out = 0.95*new + 0.05*aligned
  unsigned short kv_[8], pp_[8], hb_[8];
  #pragma unroll
  for (int k = 0; k < 8; ++k){
    int e = t + k * 1024;
    kv_[k] = keys[e];
    pp_[k] = pay[e];
    hb_[k] = keysO[e];
  }
  __syncthreads();
  #pragma unroll
  for (int k = 0; k < 8; ++k){
    float expv = b16f(o2b16(kv_[k]));
    float hs = b16f(o2b16(hb_[k]));
    float contrib = 0.05f * fmaf(0.95f, expv, 0.05f * hs);
    smem32[pp_[k]] = __float_as_uint(contrib);    // row-indexed stage (overwrites keys/pay)
  }
  __syncthreads();
  #pragma unroll
  for (int k = 0; k < 8; ++k){
    int e = t + k * 1024;
    out[(size_t)e * DIM + c] =
        fmaf(0.95f, newe[(size_t)e * DIM + c], __uint_as_float(smem32[e]));
  }
}

// fallback per-column sort (proven R3 radix, self-contained LDS) + blend staging
template<bool HASPAY>
__device__ __forceinline__ void radix_pass_fb(
    u32* srcK, u32* srcP, u32* dstK, u32* dstP,
    u32* hist, u32* totals, u32* digitbase,
    int shift, int w, int lane, int t){
  for (int i = t; i < 4096; i += 1024) hist[i] = 0;
  __syncthreads();
  u32 kreg[8], preg[8], dloc[8];
  #pragma unroll
  for (int k = 0; k < 8; ++k){
    int e = w * 512 + k * 64 + lane;
    u32 key = srcK[e];
    if (HASPAY) preg[k] = srcP[e];
    kreg[k] = key;
    u32 d = (key >> shift) & 255u;
    u64 m = ~0ull;
    #pragma unroll
    for (int b = 0; b < 8; ++b){
      u64 bb = __ballot((d >> b) & 1u);
      m &= ((d >> b) & 1u) ? bb : ~bb;
    }
    int leader = __ffsll((unsigned long long)m) - 1;
    u32 rank = (u32)__popcll(m & ((1ull << lane) - 1ull));
    u32 cntg = (u32)__popcll(m);
    u32 old = 0;
    if (lane == leader){ old = hist[w * 256 + d]; hist[w * 256 + d] = old + cntg; }
    old = (u32)__shfl((int)old, leader);
    dloc[k] = (d << 16) | (old + rank);
  }
  __syncthreads();
  if (t < 256){
    u32 run = 0;
    #pragma unroll
    for (int ww = 0; ww < 16; ++ww){
      u32 v = hist[ww * 256 + t];
      hist[ww * 256 + t] = run;
      run += v;
    }
    totals[t] = run;
  }
  __syncthreads();
  if (t < 64){
    u32 carry = 0;
    #pragma unroll
    for (int ch = 0; ch < 4; ++ch){
      u32 v = totals[ch * 64 + t];
      u32 inc = v;
      #pragma unroll
      for (int off = 1; off < 64; off <<= 1){
        u32 o = (u32)__shfl_up((int)inc, off);
        if (t >= off) inc += o;
      }
      digitbase[ch * 64 + t] = carry + inc - v;
      carry += (u32)__shfl((int)inc, 63);
    }
  }
  __syncthreads();
  #pragma unroll
  for (int k = 0; k < 8; ++k){
    u32 d = dloc[k] >> 16, off = dloc[k] & 0xFFFFu;
    u32 dst = digitbase[d] + hist[w * 256 + d] + off;
    dstK[dst] = kreg[k];
    if (HASPAY) dstP[dst] = preg[k];
  }
  __syncthreads();
}

__global__ __launch_bounds__(1024) void ksort_fb(
    const float* __restrict__ olde, float* expd_out){
  __shared__ u32 buf0[NROWS], buf1[NROWS], pay0[NROWS], pay1[NROWS];
  __shared__ u32 hist[4096], totals[256], digitbase[256];
  const int bid = blockIdx.x;
  const int c = (bid & 7) * 64 + (bid >> 3);
  const int t = threadIdx.x;
  const int lane = t & 63, w = t >> 6;

  for (int e = t; e < NROWS; e += 1024){
    buf0[e] = f2o(expd_out[(size_t)e * DIM + c]);
    pay0[e] = (u32)e;
  }
  __syncthreads();
  radix_pass_fb<true>(buf0, pay0, buf1, pay1, hist, totals, digitbase, 0,  w, lane, t);
  radix_pass_fb<true>(buf1, pay1, buf0, pay0, hist, totals, digitbase, 8,  w, lane, t);
  radix_pass_fb<true>(buf0, pay0, buf1, pay1, hist, totals, digitbase, 16, w, lane, t);
  radix_pass_fb<true>(buf1, pay1, buf0, pay0, hist, totals, digitbase, 24, w, lane, t);
  for (int e = t; e < NROWS; e += 1024)
    buf1[e] = f2o(olde[(size_t)e * DIM + c]);
  __syncthreads();
  radix_pass_fb<false>(buf1, pay1, pay1, buf1, hist, totals, digitbase, 0,  w, lane, t);
  radix_pass_fb<false>(pay1, buf1, buf1, pay1, hist, totals, digitbase, 8,  w, lane, t);
  radix_pass_fb<false>(buf1, pay1, pay1, buf1, hist, totals, digitbase, 16, w, lane, t);
  radix_pass_fb<false>(pay1, buf1, buf1, pay1, hist, totals, digitbase, 24, w, lane, t);
  for (int e = t; e < NROWS; e += 1024){
    u32 row = pay0[e];
    float expv = o2f(buf0[e]);
    float hsrc = o2f(buf1[e]);
    float aligned = expv + 0.05f * (hsrc - expv);
    pay1[row] = __float_as_uint(0.05f * aligned);
  }
  __syncthreads();
  for (int e = t; e < NROWS; e += 1024)
    expd_out[(size_t)e * DIM + c] = __uint_as_float(pay1[e]);
}

__global__ void kfinal(const float* __restrict__ newe, float* __restrict__ out){
  size_t i = (size_t)blockIdx.x * 256 + threadIdx.x;
  float4 n4 = ((const float4*)newe)[i];
  float4 o4 = ((float4*)out)[i];
  o4.x = fmaf(0.95f, n4.x, o4.x);
  o4.y = fmaf(0.95f, n4.y, o4.y);
  o4.z = fmaf(0.95f, n4.z, o4.z);
  o4.w = fmaf(0.95f, n4.w, o4.w);
  ((float4*)out)[i] = o4;
}

extern "C" void kernel_launch(void* const* d_in, const int* in_sizes, int n_in,
                              void* d_out, int out_size, void* d_ws, size_t ws_size,
                              hipStream_t stream){
  const float* olde = (const float*)d_in[0];
  const float* newe = (const float*)d_in[1];
  float* out = (float*)d_out;
  int* idx = (int*)d_ws;                                       // [0, 32KB)
  float* invn = (float*)((char*)d_ws + 32768);                 // [32KB, 64KB)

  const size_t WS_NEED = 65536 + (size_t)512 * NROWS * 2 + 65536;  // ~8.5 MB

  if (ws_size >= WS_NEED){
    // fast path: bf16 copies in d_out (dead after kgemm2; out then written by
    // ksort2); Tt/ovf/cnt in ws (dead after kresolve)
    unsigned short* Abf = (unsigned short*)d_out;                          // 8 MB
    unsigned short* Bbf = Abf + (size_t)NROWS * DIM;                       // 8 MB
    char* base = (char*)d_ws + 65536;
    u64* Tt  = (u64*)base;                                                 // 4 MB
    u64* ovf = (u64*)(base + (size_t)NROWS * 64 * 8);                      // 2 MB
    u32* cnt = (u32*)(base + (size_t)NROWS * 64 * 8 + (size_t)NROWS * OVF_CAP * 8); // 32 KB

    kconvnorm<<<2 * NROWS / 4, 256, 0, stream>>>(olde, newe, Abf, Bbf, invn, cnt);
    kgemm2<<<2048, 512, 0, stream>>>(Abf, Bbf, invn, Tt, ovf, cnt);
    kresolve<<<NROWS / 4, 256, 0, stream>>>(olde, newe, invn, Tt, ovf, cnt, idx);
    ksort2<<<DIM, 1024, 0, stream>>>(olde, newe, idx, out);
  } else {
    // fallback: proven R3 pipeline, scratch in d_out
    u64* Tt  = (u64*)d_out;                                                // 4 MB
    u64* ovf = (u64*)((char*)d_out + (size_t)NROWS * 64 * 8);              // 2 MB
    u32* cnt = (u32*)((char*)d_out + (size_t)NROWS * 64 * 8 + (size_t)NROWS * OVF_CAP * 8);

    knorm<<<NROWS / 4, 256, 0, stream>>>(newe, invn, cnt);
    kgemm_fb<<<dim3(64, 64), 256, 0, stream>>>(olde, newe, invn, Tt, ovf, cnt);
    kresolve<<<NROWS / 4, 256, 0, stream>>>(olde, newe, invn, Tt, ovf, cnt, idx);
    kexpand<<<NROWS / 2, 256, 0, stream>>>(newe, idx, out);
    ksort_fb<<<DIM, 1024, 0, stream>>>(olde, out);
    kfinal<<<NROWS * DIM / 4 / 256, 256, 0, stream>>>(newe, out);
  }
}

// Round 7
// 196.321 us; speedup vs baseline: 5.7744x; 1.2647x over previous
//
#include <hip/hip_runtime.h>
#include <hip/hip_bf16.h>
#include <stdint.h>

#define NROWS 8192
#define DIM 512
#define MARGIN 0.03f
#define OVF_CAP 32

typedef unsigned long long u64;
typedef uint32_t u32;
using bf16x8 = __attribute__((ext_vector_type(8))) short;
using ushort8 = __attribute__((ext_vector_type(8))) unsigned short;
using f32x4 = __attribute__((ext_vector_type(4))) float;

__device__ __forceinline__ u32 f2o(float f){
  u32 u = __float_as_uint(f);
  return (u & 0x80000000u) ? ~u : (u | 0x80000000u);
}
__device__ __forceinline__ float o2f(u32 o){
  u32 u = (o & 0x80000000u) ? (o & 0x7FFFFFFFu) : ~o;
  return __uint_as_float(u);
}
__device__ __forceinline__ unsigned short bfbits(float f){
  __hip_bfloat16 h = __float2bfloat16(f);
  return *reinterpret_cast<unsigned short*>(&h);
}
__device__ __forceinline__ unsigned short f2o16(unsigned short b){
  return (b & 0x8000u) ? (unsigned short)~b : (unsigned short)(b | 0x8000u);
}
__device__ __forceinline__ unsigned short o2b16(unsigned short o){
  return (o & 0x8000u) ? (unsigned short)(o & 0x7FFFu) : (unsigned short)~o;
}
__device__ __forceinline__ float b16f(unsigned short b){
  u32 u = (u32)b << 16;
  return __uint_as_float(u);
}
typedef __attribute__((address_space(1))) const void gvoid;
typedef __attribute__((address_space(3))) void svoid;
__device__ __forceinline__ void gll16(const void* g, void* l){
  __builtin_amdgcn_global_load_lds((gvoid*)g, (svoid*)l, 16, 0, 0);
}

// padded LDS index for the 8192-bin histogram: kills stride-8 bank conflicts
__device__ __forceinline__ int HIDX(int b){ return b + (b >> 5); }

// fused fp32->bf16 conversion (both inputs) + inv-norms of new rows + cnt zero.
__global__ void kconvnorm(const float* __restrict__ olde, const float* __restrict__ newe,
                          unsigned short* __restrict__ abf, unsigned short* __restrict__ bbf,
                          float* __restrict__ invn, u32* __restrict__ cnt){
  int row = blockIdx.x * 4 + (threadIdx.x >> 6);    // 0..16383
  int lane = threadIdx.x & 63;
  if (blockIdx.x < 32) cnt[blockIdx.x * 256 + threadIdx.x] = 0u;
  bool isnew = row >= NROWS;
  int r = isnew ? row - NROWS : row;
  const float* src = (isnew ? newe : olde) + (size_t)r * DIM + lane * 8;
  unsigned short* dst = (isnew ? bbf : abf) + (size_t)r * DIM + lane * 8;
  float4 v0 = *(const float4*)src, v1 = *(const float4*)(src + 4);
  ushort8 wv = { bfbits(v0.x), bfbits(v0.y), bfbits(v0.z), bfbits(v0.w),
                 bfbits(v1.x), bfbits(v1.y), bfbits(v1.z), bfbits(v1.w) };
  *(ushort8*)dst = wv;
  if (isnew){
    float s = v0.x*v0.x + v0.y*v0.y + v0.z*v0.z + v0.w*v0.w
            + v1.x*v1.x + v1.y*v1.y + v1.z*v1.z + v1.w*v1.w;
    #pragma unroll
    for (int off = 32; off > 0; off >>= 1) s += __shfl_down(s, off);
    if (lane == 0) invn[r] = 1.0f / fmaxf(sqrtf(s), 1e-8f);
  }
}

// inv norms only (fallback path)
__global__ void knorm(const float* __restrict__ x, float* __restrict__ invn,
                      u32* __restrict__ cnt){
  int row = blockIdx.x * 4 + (threadIdx.x >> 6);
  int lane = threadIdx.x & 63;
  if (threadIdx.x < 4) cnt[blockIdx.x * 4 + threadIdx.x] = 0u;
  const float4* xr = (const float4*)(x + (size_t)row * DIM);
  float s = 0.f;
  #pragma unroll
  for (int k = 0; k < 2; ++k){
    float4 v = xr[lane + 64 * k];
    s += v.x * v.x + v.y * v.y + v.z * v.z + v.w * v.w;
  }
  #pragma unroll
  for (int off = 32; off > 0; off >>= 1) s += __shfl_down(s, off);
  if (lane == 0) invn[row] = 1.0f / fmaxf(sqrtf(s), 1e-8f);
}

// common argmax epilogue: per-row tile max (over this wave's 128 cols) + margin
__device__ __forceinline__ void argmax_epilogue(
    f32x4 (&acc)[2][8], const float* __restrict__ invn,
    int m0, int n0w, int ntile, int wr, int c16, int g,
    u64* __restrict__ Tt, u64* __restrict__ ovf, u32* __restrict__ cnt){
  float invc[8];
  #pragma unroll
  for (int nj = 0; nj < 8; ++nj) invc[nj] = invn[n0w + nj * 16 + c16];
  #pragma unroll
  for (int mi = 0; mi < 2; ++mi){
    #pragma unroll
    for (int reg = 0; reg < 4; ++reg){
      float bv = -3.4e38f; int bj = 0;
      #pragma unroll
      for (int nj = 0; nj < 8; ++nj){       // ascending j in-thread -> strict > keeps lowest
        float v = acc[mi][nj][reg] * invc[nj];
        if (v > bv){ bv = v; bj = nj; }
      }
      int gj = n0w + bj * 16 + c16;
      u64 pk = ((u64)f2o(bv) << 32) | (u32)(~(u32)gj);
      #pragma unroll
      for (int m = 1; m < 16; m <<= 1){
        u64 o = __shfl_xor(pk, m);
        pk = pk > o ? pk : o;
      }
      int grow = m0 + wr * 32 + mi * 16 + g * 4 + reg;
      if (c16 == 0) Tt[(size_t)grow * 64 + ntile] = pk;
      float thr = o2f((u32)(pk >> 32)) - MARGIN;
      int tj = (int)~((u32)pk);
      #pragma unroll
      for (int nj = 0; nj < 8; ++nj){
        float v = acc[mi][nj][reg] * invc[nj];
        int j = n0w + nj * 16 + c16;
        if (v >= thr && j != tj){
          u32 pos = atomicAdd(&cnt[grow], 1u);
          if (pos < OVF_CAP) ovf[(size_t)grow * OVF_CAP + pos] = ((u64)f2o(v) << 32) | (u32)j;
        }
      }
    }
  }
}

// fast-path GEMM: 128x256 tile, 8 waves, BK=32, single-buffer, zero-conflict
// XOR swizzle (both sides), XCD rectangle. (proven R6 structure, unchanged)
__global__ __launch_bounds__(512) void kgemm2(
    const unsigned short* __restrict__ Abf, const unsigned short* __restrict__ Bbf,
    const float* __restrict__ invn, u64* __restrict__ Tt,
    u64* __restrict__ ovf, u32* __restrict__ cnt){
  __shared__ unsigned short As[128 * 32];   // 8 KB
  __shared__ unsigned short Bs[256 * 32];   // 16 KB
  const int t = threadIdx.x;
  const int lane = t & 63, w = t >> 6;      // 8 waves
  const int c16 = lane & 15, g = lane >> 4;
  const int wr = w >> 1, wc = w & 1;
  int bid = blockIdx.x;
  int xcd = bid & 7, s = bid >> 3;
  int bm = (xcd & 1) * 32 + (s >> 3);
  int bn = (xcd >> 1) * 8 + (s & 7);
  const int m0 = bm * 128, n0 = bn * 256;

  f32x4 acc[2][8];
  #pragma unroll
  for (int mi = 0; mi < 2; ++mi)
    #pragma unroll
    for (int nj = 0; nj < 8; ++nj) acc[mi][nj] = {0.f, 0.f, 0.f, 0.f};

  const int srow = t >> 2;
  const int part = t & 3;

  for (int k0 = 0; k0 < DIM; k0 += 32){
    {
      int sc = (part ^ ((srow >> 1) & 3)) * 8;
      gll16(Abf + (size_t)(m0 + srow) * DIM + k0 + sc, (void*)&As[(w * 16) * 32]);
    }
    {
      int sc = (part ^ ((srow >> 1) & 3)) * 8;
      gll16(Bbf + (size_t)(n0 + srow) * DIM + k0 + sc, (void*)&Bs[(w * 16) * 32]);
      int r2 = srow + 128;
      int sc2 = (part ^ ((r2 >> 1) & 3)) * 8;
      gll16(Bbf + (size_t)(n0 + r2) * DIM + k0 + sc2, (void*)&Bs[(128 + w * 16) * 32]);
    }
    __syncthreads();
    bf16x8 af[2], bfr[8];
    #pragma unroll
    for (int mi = 0; mi < 2; ++mi){
      int ra = wr * 32 + mi * 16 + c16;
      af[mi] = *(const bf16x8*)&As[ra * 32 + (g ^ ((ra >> 1) & 3)) * 8];
    }
    #pragma unroll
    for (int nj = 0; nj < 8; ++nj){
      int rb = wc * 128 + nj * 16 + c16;
      bfr[nj] = *(const bf16x8*)&Bs[rb * 32 + (g ^ ((rb >> 1) & 3)) * 8];
    }
    #pragma unroll
    for (int mi = 0; mi < 2; ++mi)
      #pragma unroll
      for (int nj = 0; nj < 8; ++nj)
        acc[mi][nj] = __builtin_amdgcn_mfma_f32_16x16x32_bf16(af[mi], bfr[nj], acc[mi][nj], 0, 0, 0);
    __syncthreads();
  }
  argmax_epilogue(acc, invn, m0, n0 + wc * 128, bn * 2 + wc, wr, c16, g, Tt, ovf, cnt);
}

// fallback GEMM (fp32 on-the-fly conversion; proven R3 structure)
__global__ __launch_bounds__(256) void kgemm_fb(
    const float* __restrict__ A, const float* __restrict__ B,
    const float* __restrict__ invn, u64* __restrict__ Tt,
    u64* __restrict__ ovf, u32* __restrict__ cnt){
  __shared__ short As[128 * 40];
  __shared__ short Bs[128 * 40];
  const int t = threadIdx.x;
  const int lane = t & 63, w = t >> 6;
  const int c16 = lane & 15, g = lane >> 4;
  const int m0 = blockIdx.y * 128, n0 = blockIdx.x * 128;

  f32x4 acc[2][8];
  #pragma unroll
  for (int mi = 0; mi < 2; ++mi)
    #pragma unroll
    for (int nj = 0; nj < 8; ++nj) acc[mi][nj] = {0.f, 0.f, 0.f, 0.f};

  for (int k0 = 0; k0 < DIM; k0 += 32){
    #pragma unroll
    for (int it = 0; it < 2; ++it){
      int s = t + it * 256;
      int row = s >> 2, part = s & 3;
      const float4* ga = (const float4*)(A + (size_t)(m0 + row) * DIM + k0 + part * 8);
      float4 a0 = ga[0], a1 = ga[1];
      bf16x8 ha = { (short)bfbits(a0.x), (short)bfbits(a0.y), (short)bfbits(a0.z), (short)bfbits(a0.w),
                    (short)bfbits(a1.x), (short)bfbits(a1.y), (short)bfbits(a1.z), (short)bfbits(a1.w) };
      *(bf16x8*)(&As[row * 40 + part * 8]) = ha;
      const float4* gb = (const float4*)(B + (size_t)(n0 + row) * DIM + k0 + part * 8);
      float4 b0 = gb[0], b1 = gb[1];
      bf16x8 hb = { (short)bfbits(b0.x), (short)bfbits(b0.y), (short)bfbits(b0.z), (short)bfbits(b0.w),
                    (short)bfbits(b1.x), (short)bfbits(b1.y), (short)bfbits(b1.z), (short)bfbits(b1.w) };
      *(bf16x8*)(&Bs[row * 40 + part * 8]) = hb;
    }
    __syncthreads();
    bf16x8 af[2], bfr[8];
    #pragma unroll
    for (int mi = 0; mi < 2; ++mi)
      af[mi] = *(const bf16x8*)(&As[(w * 32 + mi * 16 + c16) * 40 + g * 8]);
    #pragma unroll
    for (int nj = 0; nj < 8; ++nj)
      bfr[nj] = *(const bf16x8*)(&Bs[(nj * 16 + c16) * 40 + g * 8]);
    #pragma unroll
    for (int mi = 0; mi < 2; ++mi)
      #pragma unroll
      for (int nj = 0; nj < 8; ++nj)
        acc[mi][nj] = __builtin_amdgcn_mfma_f32_16x16x32_bf16(af[mi], bfr[nj], acc[mi][nj], 0, 0, 0);
    __syncthreads();
  }
  argmax_epilogue(acc, invn, m0, n0, blockIdx.x, w, c16, g, Tt, ovf, cnt);
}

// Stage 2: one wave per row; fast path or exact fp32 dots for window candidates
__global__ __launch_bounds__(256) void kresolve(
    const float* __restrict__ A, const float* __restrict__ B,
    const float* __restrict__ invn, const u64* __restrict__ Tt,
    const u64* __restrict__ ovf, const u32* __restrict__ cnt,
    int* __restrict__ idx){
  const int r = blockIdx.x * 4 + (threadIdx.x >> 6);
  const int lane = threadIdx.x & 63;
  u64 e = Tt[(size_t)r * 64 + lane];
  u64 m = e;
  #pragma unroll
  for (int s = 1; s < 64; s <<= 1){ u64 o = __shfl_xor(m, s); m = m > o ? m : o; }
  float W = o2f((u32)(m >> 32)) - MARGIN;
  bool inw = o2f((u32)(e >> 32)) >= W;
  u64 bal = __ballot(inw);
  u32 nov_raw = cnt[r];
  int nov = nov_raw > OVF_CAP ? OVF_CAP : (int)nov_raw;
  u64 oe = (lane < nov) ? ovf[(size_t)r * OVF_CAP + lane] : 0ull;
  bool oin = (lane < nov) && (o2f((u32)(oe >> 32)) >= W);
  u64 bal2 = __ballot(oin);
  if (nov_raw <= OVF_CAP && __popcll(bal) == 1 && bal2 == 0ull){
    if (lane == 0) idx[r] = (int)~((u32)m);
    return;
  }
  const float* ar = A + (size_t)r * DIM;
  u64 best = 0ull;
  auto eval = [&](int j){
    const float* br = B + (size_t)j * DIM;
    float s = 0.f;
    for (int k = lane; k < DIM; k += 64) s = fmaf(ar[k], br[k], s);
    #pragma unroll
    for (int o = 32; o > 0; o >>= 1) s += __shfl_xor(s, o);
    s *= invn[j];
    u64 p = ((u64)f2o(s) << 32) | (u32)(~(u32)j);
    best = best > p ? best : p;
  };
  if (nov_raw > OVF_CAP){
    for (int j = 0; j < NROWS; ++j) eval(j);   // safety net, statistically unreachable
  } else {
    u64 mm = bal;
    while (mm){
      int b = __ffsll((unsigned long long)mm) - 1;
      int j = (int)~((u32)__shfl(e, b));
      eval(j);
      mm &= mm - 1;
    }
    mm = bal2;
    while (mm){
      int b = __ffsll((unsigned long long)mm) - 1;
      int j = (int)(u32)__shfl(oe, b);
      eval(j);
      mm &= mm - 1;
    }
  }
  if (lane == 0) idx[r] = (int)~((u32)best);
}

// expanded[i][:] = new[idx[i]][:]  (fallback path only)
__global__ void kexpand(const float* __restrict__ newe, const int* __restrict__ idx,
                        float* __restrict__ expd){
  int i = blockIdx.x * 2 + (threadIdx.x >> 7);
  int c = (threadIdx.x & 127) * 4;
  int j = idx[i];
  *(float4*)(expd + (size_t)i * DIM + c) =
      *(const float4*)(newe + (size_t)j * DIM + c);
}

// block-wide exclusive scan of hist[0..8191] (padded via HIDX), in place.
// thread t owns bins [t*8, t*8+8). One internal barrier; caller barriers after.
__device__ __forceinline__ void scan8192(u32* hist, u32* wsums, int t, int lane, int w){
  u32 v[8]; u32 ts = 0;
  #pragma unroll
  for (int k = 0; k < 8; ++k){ v[k] = hist[HIDX(t * 8 + k)]; ts += v[k]; }
  u32 inc = ts;
  #pragma unroll
  for (int off = 1; off < 64; off <<= 1){
    u32 o = (u32)__shfl_up((int)inc, off);
    if (lane >= off) inc += o;
  }
  if (lane == 63) wsums[w] = inc;
  __syncthreads();
  u32 wb = 0;
  #pragma unroll
  for (int i = 0; i < 16; ++i){ u32 x = wsums[i]; if (i < w) wb += x; }
  u32 run = wb + inc - ts;                 // block-exclusive base for bin t*8
  #pragma unroll
  for (int k = 0; k < 8; ++k){ u32 x = v[k]; hist[HIDX(t * 8 + k)] = run; run += x; }
}

// per-column fused OT pipeline, counting-sort edition (non-stable, 13-bit keys).
// phase 1: counting-sort old column (bf16 values) into vals[] by rank.
// phase 2: rank expanded = new[idx[e]][c] the same way; the scattering thread
// keeps (row e -> rank) in registers, reads h_src = vals[rank], writes out.
__global__ __launch_bounds__(1024) void ksort3(
    const float* __restrict__ olde, const float* __restrict__ newe,
    const int* __restrict__ idx, float* __restrict__ out){
  __shared__ u32 hist[8448];               // 33 KB (8192 bins + pad)
  __shared__ unsigned short vals[NROWS];   // 16 KB sorted-old bf16 bits
  __shared__ u32 wsums[16];
  const int bid = blockIdx.x;
  const int c = (bid & 7) * 64 + (bid >> 3);      // XCD-grouped column
  const int t = threadIdx.x;
  const int lane = t & 63, w = t >> 6;            // 16 waves

  // ---- phase 1: old column ----
  #pragma unroll
  for (int k = 0; k < 8; ++k) hist[t + k * 1024] = 0;
  if (t < 256) hist[8192 + t] = 0;
  __syncthreads();
  unsigned short ob[8]; int oc[8];
  #pragma unroll
  for (int k = 0; k < 8; ++k){
    int e = t + k * 1024;
    ob[k] = bfbits(olde[(size_t)e * DIM + c]);
    oc[k] = (int)((u32)f2o16(ob[k]) >> 3);
    atomicAdd(&hist[HIDX(oc[k])], 1u);
  }
  __syncthreads();
  scan8192(hist, wsums, t, lane, w);
  __syncthreads();
  #pragma unroll
  for (int k = 0; k < 8; ++k){
    u32 pos = atomicAdd(&hist[HIDX(oc[k])], 1u);
    vals[pos] = ob[k];
  }
  __syncthreads();

  // ---- phase 2: expanded column ----
  #pragma unroll
  for (int k = 0; k < 8; ++k) hist[t + k * 1024] = 0;
  if (t < 256) hist[8192 + t] = 0;
  __syncthreads();
  float ev[8]; int ec[8];
  #pragma unroll
  for (int k = 0; k < 8; ++k){
    int e = t + k * 1024;
    int j = idx[e];
    float x = newe[(size_t)j * DIM + c];
    ev[k] = x;
    ec[k] = (int)((u32)f2o16(bfbits(x)) >> 3);
    atomicAdd(&hist[HIDX(ec[k])], 1u);
  }
  __syncthreads();
  scan8192(hist, wsums, t, lane, w);
  __syncthreads();
  #pragma unroll
  for (int k = 0; k < 8; ++k){
    int e = t + k * 1024;
    u32 pos = atomicAdd(&hist[HIDX(ec[k])], 1u);   // rank of row e (ties arbitrary)
    float hsrc = b16f(vals[pos]);
    float aligned = fmaf(0.95f, ev[k], 0.05f * hsrc);
    out[(size_t)e * DIM + c] = fmaf(0.95f, newe[(size_t)e * DIM + c], 0.05f * aligned);
  }
}

// fallback per-column sort (proven R3 radix, self-contained LDS) + blend staging
template<bool HASPAY>
__device__ __forceinline__ void radix_pass_fb(
    u32* srcK, u32* srcP, u32* dstK, u32* dstP,
    u32* hist, u32* totals, u32* digitbase,
    int shift, int w, int lane, int t){
  for (int i = t; i < 4096; i += 1024) hist[i] = 0;
  __syncthreads();
  u32 kreg[8], preg[8], dloc[8];
  #pragma unroll
  for (int k = 0; k < 8; ++k){
    int e = w * 512 + k * 64 + lane;
    u32 key = srcK[e];
    if (HASPAY) preg[k] = srcP[e];
    kreg[k] = key;
    u32 d = (key >> shift) & 255u;
    u64 m = ~0ull;
    #pragma unroll
    for (int b = 0; b < 8; ++b){
      u64 bb = __ballot((d >> b) & 1u);
      m &= ((d >> b) & 1u) ? bb : ~bb;
    }
    int leader = __ffsll((unsigned long long)m) - 1;
    u32 rank = (u32)__popcll(m & ((1ull << lane) - 1ull));
    u32 cntg = (u32)__popcll(m);
    u32 old = 0;
    if (lane == leader){ old = hist[w * 256 + d]; hist[w * 256 + d] = old + cntg; }
    old = (u32)__shfl((int)old, leader);
    dloc[k] = (d << 16) | (old + rank);
  }
  __syncthreads();
  if (t < 256){
    u32 run = 0;
    #pragma unroll
    for (int ww = 0; ww < 16; ++ww){
      u32 v = hist[ww * 256 + t];
      hist[ww * 256 + t] = run;
      run += v;
    }
    totals[t] = run;
  }
  __syncthreads();
  if (t < 64){
    u32 carry = 0;
    #pragma unroll
    for (int ch = 0; ch < 4; ++ch){
      u32 v = totals[ch * 64 + t];
      u32 inc = v;
      #pragma unroll
      for (int off = 1; off < 64; off <<= 1){
        u32 o = (u32)__shfl_up((int)inc, off);
        if (t >= off) inc += o;
      }
      digitbase[ch * 64 + t] = carry + inc - v;
      carry += (u32)__shfl((int)inc, 63);
    }
  }
  __syncthreads();
  #pragma unroll
  for (int k = 0; k < 8; ++k){
    u32 d = dloc[k] >> 16, off = dloc[k] & 0xFFFFu;
    u32 dst = digitbase[d] + hist[w * 256 + d] + off;
    dstK[dst] = kreg[k];
    if (HASPAY) dstP[dst] = preg[k];
  }
  __syncthreads();
}

__global__ __launch_bounds__(1024) void ksort_fb(
    const float* __restrict__ olde, float* expd_out){
  __shared__ u32 buf0[NROWS], buf1[NROWS], pay0[NROWS], pay1[NROWS];
  __shared__ u32 hist[4096], totals[256], digitbase[256];
  const int bid = blockIdx.x;
  const int c = (bid & 7) * 64 + (bid >> 3);
  const int t = threadIdx.x;
  const int lane = t & 63, w = t >> 6;

  for (int e = t; e < NROWS; e += 1024){
    buf0[e] = f2o(expd_out[(size_t)e * DIM + c]);
    pay0[e] = (u32)e;
  }
  __syncthreads();
  radix_pass_fb<true>(buf0, pay0, buf1, pay1, hist, totals, digitbase, 0,  w, lane, t);
  radix_pass_fb<true>(buf1, pay1, buf0, pay0, hist, totals, digitbase, 8,  w, lane, t);
  radix_pass_fb<true>(buf0, pay0, buf1, pay1, hist, totals, digitbase, 16, w, lane, t);
  radix_pass_fb<true>(buf1, pay1, buf0, pay0, hist, totals, digitbase, 24, w, lane, t);
  for (int e = t; e < NROWS; e += 1024)
    buf1[e] = f2o(olde[(size_t)e * DIM + c]);
  __syncthreads();
  radix_pass_fb<false>(buf1, pay1, pay1, buf1, hist, totals, digitbase, 0,  w, lane, t);
  radix_pass_fb<false>(pay1, buf1, buf1, pay1, hist, totals, digitbase, 8,  w, lane, t);
  radix_pass_fb<false>(buf1, pay1, pay1, buf1, hist, totals, digitbase, 16, w, lane, t);
  radix_pass_fb<false>(pay1, buf1, buf1, pay1, hist, totals, digitbase, 24, w, lane, t);
  for (int e = t; e < NROWS; e += 1024){
    u32 row = pay0[e];
    float expv = o2f(buf0[e]);
    float hsrc = o2f(buf1[e]);
    float aligned = expv + 0.05f * (hsrc - expv);
    pay1[row] = __float_as_uint(0.05f * aligned);
  }
  __syncthreads();
  for (int e = t; e < NROWS; e += 1024)
    expd_out[(size_t)e * DIM + c] = __uint_as_float(pay1[e]);
}

__global__ void kfinal(const float* __restrict__ newe, float* __restrict__ out){
  size_t i = (size_t)blockIdx.x * 256 + threadIdx.x;
  float4 n4 = ((const float4*)newe)[i];
  float4 o4 = ((float4*)out)[i];
  o4.x = fmaf(0.95f, n4.x, o4.x);
  o4.y = fmaf(0.95f, n4.y, o4.y);
  o4.z = fmaf(0.95f, n4.z, o4.z);
  o4.w = fmaf(0.95f, n4.w, o4.w);
  ((float4*)out)[i] = o4;
}

extern "C" void kernel_launch(void* const* d_in, const int* in_sizes, int n_in,
                              void* d_out, int out_size, void* d_ws, size_t ws_size,
                              hipStream_t stream){
  const float* olde = (const float*)d_in[0];
  const float* newe = (const float*)d_in[1];
  float* out = (float*)d_out;
  int* idx = (int*)d_ws;                                       // [0, 32KB)
  float* invn = (float*)((char*)d_ws + 32768);                 // [32KB, 64KB)

  const size_t WS_NEED = 65536 + (size_t)512 * NROWS * 2 + 65536;  // ~8.5 MB

  if (ws_size >= WS_NEED){
    // fast path: bf16 copies in d_out (dead after kgemm2; out then fully
    // rewritten by ksort3); Tt/ovf/cnt in ws (dead after kresolve)
    unsigned short* Abf = (unsigned short*)d_out;                          // 8 MB
    unsigned short* Bbf = Abf + (size_t)NROWS * DIM;                       // 8 MB
    char* base = (char*)d_ws + 65536;
    u64* Tt  = (u64*)base;                                                 // 4 MB
    u64* ovf = (u64*)(base + (size_t)NROWS * 64 * 8);                      // 2 MB
    u32* cnt = (u32*)(base + (size_t)NROWS * 64 * 8 + (size_t)NROWS * OVF_CAP * 8); // 32 KB

    kconvnorm<<<2 * NROWS / 4, 256, 0, stream>>>(olde, newe, Abf, Bbf, invn, cnt);
    kgemm2<<<2048, 512, 0, stream>>>(Abf, Bbf, invn, Tt, ovf, cnt);
    kresolve<<<NROWS / 4, 256, 0, stream>>>(olde, newe, invn, Tt, ovf, cnt, idx);
    ksort3<<<DIM, 1024, 0, stream>>>(olde, newe, idx, out);
  } else {
    // fallback: proven R3 pipeline, scratch in d_out
    u64* Tt  = (u64*)d_out;                                                // 4 MB
    u64* ovf = (u64*)((char*)d_out + (size_t)NROWS * 64 * 8);              // 2 MB
    u32* cnt = (u32*)((char*)d_out + (size_t)NROWS * 64 * 8 + (size_t)NROWS * OVF_CAP * 8);

    knorm<<<NROWS / 4, 256, 0, stream>>>(newe, invn, cnt);
    kgemm_fb<<<dim3(64, 64), 256, 0, stream>>>(olde, newe, invn, Tt, ovf, cnt);
    kresolve<<<NROWS / 4, 256, 0, stream>>>(olde, newe, invn, Tt, ovf, cnt, idx);
    kexpand<<<NROWS / 2, 256, 0, stream>>>(newe, idx, out);
    ksort_fb<<<DIM, 1024, 0, stream>>>(olde, out);
    kfinal<<<NROWS * DIM / 4 / 256, 256, 0, stream>>>(newe, out);
  }
}